// Round 13
// baseline (19401.698 us; speedup 1.0000x reference)
//
#include <hip/hip_runtime.h>
#include <hip/hip_fp16.h>

#define B_SZ    64
#define T_STEPS 512
#define U1      128
#define S1      128
#define U2      256
#define S2      128
#define NUNF    6
#define RC2     6       // ltc2: LDS-resident chunks (of 16) per group

typedef _Float16 h2f __attribute__((ext_vector_type(2)));

__device__ __forceinline__ float fast_exp2(float x) { return __builtin_amdgcn_exp2f(x); }
__device__ __forceinline__ float fast_rcp(float x)  { return __builtin_amdgcn_rcpf(x); }
__device__ __forceinline__ h2f u2h(unsigned u) { union { unsigned x; h2f h; } c; c.x = u; return c.h; }
__device__ __forceinline__ h2f pkrtz(float a, float b)
{
    return __builtin_bit_cast(h2f, __builtin_amdgcn_cvt_pkrtz(a, b));
}

// ---------------------------------------------------------------------------
// eval 4 synapse pairs: AB half2(A=sig*log2e, B=mu*sig*log2e), W half(w*erev).
// sigmoid((v-mu)*sig) = 1/(1+exp2(B-A*v)); |W| = w*mask (w>0).
// BATCHED RCP: one v_rcp for all 4 pairs via prefix/suffix products
// (d <= 1+2^26, 4-product <= 2e31 < fp32 max; ~3 ulp extra, << fp16 noise).
// trans ops per chunk: 8 -> 5 (4 exp2 + 1 rcp).
// ---------------------------------------------------------------------------
__device__ __forceinline__ void eval4d(uint4 ab4, uint2 w2, float4 vv,
                                       float& an, float& ad)
{
    h2f ab0 = u2h(ab4.x), ab1 = u2h(ab4.y), ab2 = u2h(ab4.z), ab3 = u2h(ab4.w);
    float d0 = 1.f + fast_exp2(fmaf(-(float)ab0[0], vv.x, (float)ab0[1]));
    float d1 = 1.f + fast_exp2(fmaf(-(float)ab1[0], vv.y, (float)ab1[1]));
    float d2 = 1.f + fast_exp2(fmaf(-(float)ab2[0], vv.z, (float)ab2[1]));
    float d3 = 1.f + fast_exp2(fmaf(-(float)ab3[0], vv.w, (float)ab3[1]));
    float p01 = d0 * d1, p23 = d2 * d3;
    float R   = fast_rcp(p01 * p23);
    float q01 = p23 * R;                 // = 1/(d0*d1)
    float q23 = p01 * R;                 // = 1/(d2*d3)
    h2f rp01 = pkrtz(d1 * q01, d0 * q01);
    h2f rp23 = pkrtz(d3 * q23, d2 * q23);
    an = __builtin_amdgcn_fdot2(u2h(w2.x), rp01, an, false);
    an = __builtin_amdgcn_fdot2(u2h(w2.y), rp23, an, false);
    ad = __builtin_amdgcn_fdot2(u2h(w2.x & 0x7FFF7FFFu), rp01, ad, false);
    ad = __builtin_amdgcn_fdot2(u2h(w2.y & 0x7FFF7FFFu), rp23, ad, false);
}

// ---------------------------------------------------------------------------
// prep: chunked packing, interleaved layout [c][u][g]: s4 = g*CPG + c,
// out index (c*U + uo)*NG + g.  Lane (u,g) then reads entry c*U*NG + tid.
// ---------------------------------------------------------------------------
__global__ void prep_ilv(const float* __restrict__ sg, const float* __restrict__ mu,
                         const float* __restrict__ w, const float* __restrict__ er,
                         uint4* __restrict__ ABI, uint2* __restrict__ WI,
                         int S4, int U, int CPG, int NG)
{
    int i = blockIdx.x * 256 + threadIdx.x;
    if (i >= S4 * U) return;
    int uo = i % U, s4 = i / U;
    int g = s4 / CPG, c = s4 % CPG;
    const float L2E = 1.4426950408889634f;
    unsigned ab[4]; __half wh[4];
    #pragma unroll
    for (int q = 0; q < 4; ++q) {
        size_t idx = (size_t)(s4 * 4 + q) * U + uo;
        float a = sg[idx] * L2E;
        __half2 h = __floats2half2_rn(a, mu[idx] * a);
        ab[q] = *reinterpret_cast<unsigned*>(&h);
        wh[q] = __float2half_rn(w[idx] * er[idx]);
    }
    __half2 w01 = __halves2half2(wh[0], wh[1]);
    __half2 w23 = __halves2half2(wh[2], wh[3]);
    int o = (c * U + uo) * NG + g;
    ABI[o] = make_uint4(ab[0], ab[1], ab[2], ab[3]);
    WI[o]  = make_uint2(*reinterpret_cast<unsigned*>(&w01),
                        *reinterpret_cast<unsigned*>(&w23));
}

// linear fp16 pack (sens1k / sens2k)
__global__ void prep_half(const float* __restrict__ sg, const float* __restrict__ mu,
                          const float* __restrict__ w, const float* __restrict__ er,
                          __half2* __restrict__ AB, __half* __restrict__ W, int n)
{
    int i = blockIdx.x * 256 + threadIdx.x;
    if (i >= n) return;
    const float L2E = 1.4426950408889634f;
    float a = sg[i] * L2E;
    AB[i] = __floats2half2_rn(a, mu[i] * a);
    W[i]  = __float2half_rn(w[i] * er[i]);
}

__global__ void prep_vec(const float* __restrict__ gleak, const float* __restrict__ vleak,
                         const float* __restrict__ cm,
                         float* __restrict__ cmt, float* __restrict__ nb,
                         float* __restrict__ db, int n)
{
    int i = blockIdx.x * 256 + threadIdx.x;
    if (i >= n) return;
    float c6 = cm[i] * 6.f;
    float gl = gleak[i];
    cmt[i] = c6;
    nb[i]  = gl * vleak[i];
    db[i]  = c6 + gl + 1e-8f;
}

// ---------------------------------------------------------------------------
// Layer-1 sensory sums, fully parallel over (b,t): all 256 CUs.
// ---------------------------------------------------------------------------
__global__ __launch_bounds__(256, 4) void sens1k(
    const float* __restrict__ x,
    const float* __restrict__ in_w, const float* __restrict__ in_b,
    const __half2* __restrict__ ABs, const __half* __restrict__ Ws,
    float* __restrict__ sn, float* __restrict__ sd)
{
    const int tid = threadIdx.x;
    const int b   = blockIdx.x >> 6;
    const int t0  = (blockIdx.x & 63) << 3;
    const int u   = tid & 127;
    const int hf  = tid >> 7;

    __shared__ float ibu[8][S1];
    for (int idx = tid; idx < 8 * S1; idx += 256) {
        int tt = idx >> 7, s = idx & (S1 - 1);
        ibu[tt][s] = fmaf(x[((size_t)b * T_STEPS + t0 + tt) * S1 + s], in_w[s], in_b[s]);
    }
    __syncthreads();

    float an0 = 0, an1 = 0, an2 = 0, an3 = 0;
    float ad0 = 0, ad1 = 0, ad2 = 0, ad3 = 0;
    const int tb = hf * 4;
    for (int s = 0; s < S1; ++s) {
        __half2 ab = ABs[(size_t)s * U1 + u];
        float a  = __low2float(ab);
        float bb = __high2float(ab);
        float ww = __half2float(Ws[(size_t)s * U1 + u]);
        float aw = fabsf(ww);
        float d0 = 1.f + fast_exp2(fmaf(-a, ibu[tb + 0][s], bb));
        float d1 = 1.f + fast_exp2(fmaf(-a, ibu[tb + 1][s], bb));
        float d2 = 1.f + fast_exp2(fmaf(-a, ibu[tb + 2][s], bb));
        float d3 = 1.f + fast_exp2(fmaf(-a, ibu[tb + 3][s], bb));
        float p01 = d0 * d1, p23 = d2 * d3;
        float R   = fast_rcp(p01 * p23);
        float q01 = p23 * R, q23 = p01 * R;
        float r0 = d1 * q01, r1 = d0 * q01, r2 = d3 * q23, r3 = d2 * q23;
        an0 = fmaf(ww, r0, an0); ad0 = fmaf(aw, r0, ad0);
        an1 = fmaf(ww, r1, an1); ad1 = fmaf(aw, r1, ad1);
        an2 = fmaf(ww, r2, an2); ad2 = fmaf(aw, r2, ad2);
        an3 = fmaf(ww, r3, an3); ad3 = fmaf(aw, r3, ad3);
    }
    size_t base = ((size_t)b * T_STEPS + t0 + tb) * U1 + u;
    sn[base]          = an0; sd[base]          = ad0;
    sn[base + U1]     = an1; sd[base + U1]     = ad1;
    sn[base + 2 * U1] = an2; sd[base + 2 * U1] = ad2;
    sn[base + 3 * U1] = an3; sd[base + 3 * U1] = ad3;
}

// ---------------------------------------------------------------------------
// Layer 1, butterfly: 1024 thr = 16 waves. lane = ul*8+g; u = w*8+ul.
// ALL recurrent params LDS-resident.  ONE barrier per unfold.
// ---------------------------------------------------------------------------
template <bool HOIST1>
__global__ __launch_bounds__(1024, 1) void ltc1(
    const float* __restrict__ x,
    const float* __restrict__ in_w, const float* __restrict__ in_b,
    const uint4* __restrict__ ABsI, const uint2* __restrict__ WsI,
    const uint4* __restrict__ ABrI, const uint2* __restrict__ WrI,
    const float* __restrict__ sn, const float* __restrict__ sd,
    const float* __restrict__ cmt, const float* __restrict__ nbv, const float* __restrict__ dbv,
    const float* __restrict__ ow, const float* __restrict__ ob,
    float* __restrict__ h1)
{
    const int b    = blockIdx.x;
    const int tid  = threadIdx.x;
    const int w    = tid >> 6;
    const int lane = tid & 63;
    const int g    = lane & 7;
    const int ul   = lane >> 3;
    const int u    = w * 8 + ul;

    __shared__ uint4 ABl[4 * 1024];
    __shared__ uint2 Wl[4 * 1024];
    __shared__ float vbuf[2][8][20];
    __shared__ float ibuf[S1];

    for (int idx = tid; idx < 4 * 1024; idx += 1024) {
        ABl[idx] = ABrI[idx];
        Wl[idx]  = WrI[idx];
    }
    for (int idx = tid; idx < 2 * 8 * 20; idx += 1024)
        (&vbuf[0][0][0])[idx] = 0.f;

    float v_reg = 0.f;
    const float c_cmt = cmt[u], c_nb = nbv[u], c_db = dbv[u];
    const float c_ow = ow[u], c_ob = ob[u];
    float c_iw = 0.f, c_ib = 0.f;
    if (!HOIST1 && tid < S1) { c_iw = in_w[tid]; c_ib = in_b[tid]; }

    const float* xb = x  + (size_t)b * T_STEPS * S1;
    float*       hb = h1 + (size_t)b * T_STEPS * U1;
    const uint4* pABs = ABsI + tid;
    const uint2* pWs  = WsI  + tid;

    __syncthreads();
    int buf = 0;

    // prefetch step-0 hoisted sums
    float pf_n = 0.f, pf_d = 0.f;
    if (HOIST1) {
        size_t ro = ((size_t)b * T_STEPS) * U1 + u;
        pf_n = sn[ro]; pf_d = sd[ro];
    }

    for (int t = 0; t < T_STEPS; ++t) {
        float nb_t, db_t;
        if (HOIST1) {
            nb_t = c_nb + pf_n;
            db_t = c_db + pf_d;
            if (t + 1 < T_STEPS) {
                size_t ro = ((size_t)b * T_STEPS + t + 1) * U1 + u;
                pf_n = sn[ro]; pf_d = sd[ro];
            }
        } else {
            if (tid < S1) ibuf[tid] = fmaf(xb[(size_t)t * S1 + tid], c_iw, c_ib);
            __syncthreads();
            float an = 0.f, ad = 0.f;
            #pragma unroll
            for (int c = 0; c < 4; ++c) {
                uint4 ab = pABs[c * 1024];
                uint2 w2 = pWs[c * 1024];
                float4 vv = *reinterpret_cast<const float4*>(&ibuf[g * 16 + c * 4]);
                eval4d(ab, w2, vv, an, ad);
            }
            an += __shfl_xor(an, 1, 64); ad += __shfl_xor(ad, 1, 64);
            an += __shfl_xor(an, 2, 64); ad += __shfl_xor(ad, 2, 64);
            an += __shfl_xor(an, 4, 64); ad += __shfl_xor(ad, 4, 64);
            nb_t = c_nb + an; db_t = c_db + ad;
        }

        #pragma unroll 1
        for (int k = 0; k < NUNF; ++k) {
            float an = 0.f, ad = 0.f;
            const float* vb = &vbuf[buf][g][0];
            #pragma unroll
            for (int c = 0; c < 4; ++c) {
                uint4 ab = ABl[c * 1024 + tid];
                uint2 w2 = Wl[c * 1024 + tid];
                float4 vv = *reinterpret_cast<const float4*>(&vb[c * 4]);
                eval4d(ab, w2, vv, an, ad);
            }
            an += __shfl_xor(an, 1, 64); ad += __shfl_xor(ad, 1, 64);
            an += __shfl_xor(an, 2, 64); ad += __shfl_xor(ad, 2, 64);
            an += __shfl_xor(an, 4, 64); ad += __shfl_xor(ad, 4, 64);
            float wn = nb_t + an;
            float wd = db_t + ad;
            v_reg = fmaf(c_cmt, v_reg, wn) * fast_rcp(wd);
            if (g == 0) vbuf[buf ^ 1][w >> 1][(w & 1) * 8 + ul] = v_reg;
            buf ^= 1;
            __syncthreads();
        }
        if (g == 0) hb[(size_t)t * U1 + u] = fmaf(v_reg, c_ow, c_ob);
    }
}

// ---------------------------------------------------------------------------
// Layer-2 sensory sums, fully parallel over (b,t).
// ---------------------------------------------------------------------------
__global__ __launch_bounds__(256, 4) void sens2k(
    const float* __restrict__ h1,
    const float* __restrict__ in_w, const float* __restrict__ in_b,
    const __half2* __restrict__ ABs, const __half* __restrict__ Ws,
    float* __restrict__ sn, float* __restrict__ sd)
{
    const int tid = threadIdx.x;
    const int b   = blockIdx.x >> 7;
    const int t0  = (blockIdx.x & 127) << 2;

    __shared__ float ibu[4][S2];
    for (int idx = tid; idx < 4 * S2; idx += 256) {
        int tt = idx >> 7, s = idx & (S2 - 1);
        ibu[tt][s] = fmaf(h1[((size_t)b * T_STEPS + t0 + tt) * S2 + s], in_w[s], in_b[s]);
    }
    __syncthreads();

    const int u = tid;
    float an0 = 0, an1 = 0, an2 = 0, an3 = 0;
    float ad0 = 0, ad1 = 0, ad2 = 0, ad3 = 0;
    for (int s = 0; s < S2; ++s) {
        __half2 ab = ABs[(size_t)s * U2 + u];
        float a  = __low2float(ab);
        float bb = __high2float(ab);
        float ww = __half2float(Ws[(size_t)s * U2 + u]);
        float aw = fabsf(ww);
        float d0 = 1.f + fast_exp2(fmaf(-a, ibu[0][s], bb));
        float d1 = 1.f + fast_exp2(fmaf(-a, ibu[1][s], bb));
        float d2 = 1.f + fast_exp2(fmaf(-a, ibu[2][s], bb));
        float d3 = 1.f + fast_exp2(fmaf(-a, ibu[3][s], bb));
        float p01 = d0 * d1, p23 = d2 * d3;
        float R   = fast_rcp(p01 * p23);
        float q01 = p23 * R, q23 = p01 * R;
        float r0 = d1 * q01, r1 = d0 * q01, r2 = d3 * q23, r3 = d2 * q23;
        an0 = fmaf(ww, r0, an0); ad0 = fmaf(aw, r0, ad0);
        an1 = fmaf(ww, r1, an1); ad1 = fmaf(aw, r1, ad1);
        an2 = fmaf(ww, r2, an2); ad2 = fmaf(aw, r2, ad2);
        an3 = fmaf(ww, r3, an3); ad3 = fmaf(aw, r3, ad3);
    }
    size_t base = ((size_t)b * T_STEPS + t0) * U2 + u;
    sn[base]          = an0; sd[base]          = ad0;
    sn[base + U2]     = an1; sd[base + U2]     = ad1;
    sn[base + 2 * U2] = an2; sd[base + 2 * U2] = ad2;
    sn[base + 3 * U2] = an3; sd[base + 3 * U2] = ad3;
}

// ---------------------------------------------------------------------------
// Layer 2, butterfly (round-12 structure + batched-rcp eval + sn/sd prefetch).
// ---------------------------------------------------------------------------
template <bool HOIST>
__global__ __launch_bounds__(1024, 1) void ltc2(
    const float* __restrict__ h1,
    const float* __restrict__ in_w, const float* __restrict__ in_b,
    const uint4* __restrict__ ABsI, const uint2* __restrict__ WsI,
    const uint4* __restrict__ ABrI, const uint2* __restrict__ WrI,
    const float* __restrict__ sn, const float* __restrict__ sd,
    const float* __restrict__ cmt, const float* __restrict__ nbv, const float* __restrict__ dbv,
    const float* __restrict__ ow, const float* __restrict__ ob,
    float* __restrict__ h2)
{
    const int b    = blockIdx.x;
    const int tid  = threadIdx.x;
    const int w    = tid >> 6;
    const int lane = tid & 63;
    const int g    = lane & 3;
    const int ul   = lane >> 2;
    const int u    = w * 16 + ul;

    __shared__ uint4 ABl[RC2 * U2 * 4];
    __shared__ uint2 Wl[RC2 * U2 * 4];
    __shared__ float vbuf[2][4][68];
    __shared__ float ibuf[S2];

    for (int idx = tid; idx < RC2 * U2 * 4; idx += 1024) {
        ABl[idx] = ABrI[idx];
        Wl[idx]  = WrI[idx];
    }
    for (int idx = tid; idx < 2 * 4 * 68; idx += 1024)
        (&vbuf[0][0][0])[idx] = 0.f;

    const uint4* pABr = ABrI + u * 4 + g;
    const uint2* pWr  = WrI  + u * 4 + g;
    const uint4* pABs = ABsI + u * 4 + g;
    const uint2* pWs  = WsI  + u * 4 + g;

    float v_reg = 0.f;
    const float c_cmt = cmt[u], c_nb = nbv[u], c_db = dbv[u];
    float c_ow = 0.f, c_ob = 0.f;
    if (u < 64) { c_ow = ow[u]; c_ob = ob[u]; }
    float c_iw = 0.f, c_ib = 0.f;
    if (!HOIST && tid < S2) { c_iw = in_w[tid]; c_ib = in_b[tid]; }

    const float* hb = h1 + (size_t)b * T_STEPS * S2;
    float*       op = h2 + (size_t)b * T_STEPS * 64;

    __syncthreads();
    int buf = 0;

    float pf_n = 0.f, pf_d = 0.f;
    if (HOIST) {
        size_t ro = ((size_t)b * T_STEPS) * U2 + u;
        pf_n = sn[ro]; pf_d = sd[ro];
    }

    for (int t = 0; t < T_STEPS; ++t) {
        float nb_t, db_t;
        if (HOIST) {
            nb_t = c_nb + pf_n;
            db_t = c_db + pf_d;
            if (t + 1 < T_STEPS) {
                size_t ro = ((size_t)b * T_STEPS + t + 1) * U2 + u;
                pf_n = sn[ro]; pf_d = sd[ro];
            }
        } else {
            if (tid < S2) ibuf[tid] = fmaf(hb[(size_t)t * S2 + tid], c_iw, c_ib);
            __syncthreads();
            float an = 0.f, ad = 0.f;
            #pragma unroll 2
            for (int c = 0; c < 8; ++c) {
                uint4 ab = pABs[c * 1024];
                uint2 w2 = pWs[c * 1024];
                float4 vv = *reinterpret_cast<const float4*>(&ibuf[g * 32 + c * 4]);
                eval4d(ab, w2, vv, an, ad);
            }
            an += __shfl_xor(an, 1, 64); ad += __shfl_xor(ad, 1, 64);
            an += __shfl_xor(an, 2, 64); ad += __shfl_xor(ad, 2, 64);
            nb_t = c_nb + an; db_t = c_db + ad;
        }

        #pragma unroll 1
        for (int k = 0; k < NUNF; ++k) {
            float anL = 0.f, adL = 0.f, anR = 0.f, adR = 0.f;
            const float* vb = &vbuf[buf][g][0];
            #pragma unroll
            for (int c = 0; c < RC2; ++c) {
                uint4 ab = ABl[c * 1024 + tid];
                uint2 w2 = Wl[c * 1024 + tid];
                float4 vv = *reinterpret_cast<const float4*>(&vb[c * 4]);
                eval4d(ab, w2, vv, anL, adL);
            }
            #pragma unroll 2
            for (int c = RC2; c < 16; ++c) {
                uint4 ab = pABr[c * 1024];
                uint2 w2 = pWr[c * 1024];
                float4 vv = *reinterpret_cast<const float4*>(&vb[c * 4]);
                eval4d(ab, w2, vv, anR, adR);
            }
            float an = anL + anR, ad = adL + adR;
            an += __shfl_xor(an, 1, 64); ad += __shfl_xor(ad, 1, 64);
            an += __shfl_xor(an, 2, 64); ad += __shfl_xor(ad, 2, 64);
            float wn = nb_t + an;
            float wd = db_t + ad;
            v_reg = fmaf(c_cmt, v_reg, wn) * fast_rcp(wd);
            if (g == 0) vbuf[buf ^ 1][w >> 2][(w & 3) * 16 + ul] = v_reg;
            buf ^= 1;
            __syncthreads();
        }
        if (u < 64 && g == 0) op[(size_t)t * 64 + u] = fmaf(v_reg, c_ow, c_ob);
    }
}

// ---------------------------------------------------------------------------
// FC head: out[b,t,o] = fcb[o] + sum_k h2[b,t,k] * fcw[o,k]
// ---------------------------------------------------------------------------
__global__ __launch_bounds__(512, 1) void fc_head(
    const float* __restrict__ h2, const float* __restrict__ fcw,
    const float* __restrict__ fcb, float* __restrict__ out)
{
    __shared__ float fwT[64 * 64];
    __shared__ float hs[8 * 64];
    const int tid = threadIdx.x;
    for (int i = tid; i < 64 * 64; i += 512) {
        int o = i >> 6, k = i & 63;
        fwT[k * 64 + o] = fcw[i];
    }
    size_t base = (size_t)blockIdx.x * 8 * 64;
    hs[tid] = h2[base + tid];
    __syncthreads();
    const int o = tid & 63, tt = tid >> 6;
    float acc = fcb[o];
    #pragma unroll
    for (int k = 0; k < 64; ++k)
        acc = fmaf(hs[tt * 64 + k], fwT[k * 64 + o], acc);
    out[base + tt * 64 + o] = acc;
}

// ---------------------------------------------------------------------------
extern "C" void kernel_launch(void* const* d_in, const int* in_sizes, int n_in,
                              void* d_out, int out_size, void* d_ws, size_t ws_size,
                              hipStream_t stream)
{
    (void)in_sizes; (void)n_in; (void)out_size;

    const float* x      = (const float*)d_in[0];
    const float* l1_iw  = (const float*)d_in[1];
    const float* l1_ib  = (const float*)d_in[2];
    const float* l1_sw  = (const float*)d_in[3];
    const float* l1_ss  = (const float*)d_in[4];
    const float* l1_smu = (const float*)d_in[5];
    const float* l1_se  = (const float*)d_in[6];
    const float* l1_w   = (const float*)d_in[8];
    const float* l1_sg  = (const float*)d_in[9];
    const float* l1_mu  = (const float*)d_in[10];
    const float* l1_er  = (const float*)d_in[11];
    const float* l1_gl  = (const float*)d_in[13];
    const float* l1_vl  = (const float*)d_in[14];
    const float* l1_cm  = (const float*)d_in[15];
    const float* l1_ow  = (const float*)d_in[16];
    const float* l1_ob  = (const float*)d_in[17];
    const float* l2_iw  = (const float*)d_in[18];
    const float* l2_ib  = (const float*)d_in[19];
    const float* l2_sw  = (const float*)d_in[20];
    const float* l2_ss  = (const float*)d_in[21];
    const float* l2_smu = (const float*)d_in[22];
    const float* l2_se  = (const float*)d_in[23];
    const float* l2_w   = (const float*)d_in[25];
    const float* l2_sg  = (const float*)d_in[26];
    const float* l2_mu  = (const float*)d_in[27];
    const float* l2_er  = (const float*)d_in[28];
    const float* l2_gl  = (const float*)d_in[30];
    const float* l2_vl  = (const float*)d_in[31];
    const float* l2_cm  = (const float*)d_in[32];
    const float* l2_ow  = (const float*)d_in[33];
    const float* l2_ob  = (const float*)d_in[34];
    const float* fcw    = (const float*)d_in[35];
    const float* fcb    = (const float*)d_in[36];

    char*  base = (char*)d_ws;
    size_t off  = 0;
    auto alloc = [&](size_t bytes) -> char* {
        char* p = base + off;
        off += (bytes + 255) & ~(size_t)255;
        return p;
    };

    float* h1 = (float*)alloc((size_t)B_SZ * T_STEPS * U1 * 4);
    float* h2 = (float*)alloc((size_t)B_SZ * T_STEPS * 64 * 4);
    uint4* ABsI1 = (uint4*)alloc((size_t)(S1 / 4) * U1 * 16);
    uint2* WsI1  = (uint2*)alloc((size_t)(S1 / 4) * U1 * 8);
    uint4* ABrI1 = (uint4*)alloc((size_t)(U1 / 4) * U1 * 16);
    uint2* WrI1  = (uint2*)alloc((size_t)(U1 / 4) * U1 * 8);
    uint4* ABsI2 = (uint4*)alloc((size_t)(S2 / 4) * U2 * 16);
    uint2* WsI2  = (uint2*)alloc((size_t)(S2 / 4) * U2 * 8);
    uint4* ABrI2 = (uint4*)alloc((size_t)(U2 / 4) * U2 * 16);
    uint2* WrI2  = (uint2*)alloc((size_t)(U2 / 4) * U2 * 8);
    __half2* AB1s = (__half2*)alloc((size_t)S1 * U1 * 4);
    __half*  W1s  = (__half*) alloc((size_t)S1 * U1 * 2);
    __half2* AB2s = (__half2*)alloc((size_t)S2 * U2 * 4);
    __half*  W2s  = (__half*) alloc((size_t)S2 * U2 * 2);
    float* cmt1 = (float*)alloc(U1 * 4);
    float* nb1  = (float*)alloc(U1 * 4);
    float* db1  = (float*)alloc(U1 * 4);
    float* cmt2 = (float*)alloc(U2 * 4);
    float* nb2  = (float*)alloc(U2 * 4);
    float* db2  = (float*)alloc(U2 * 4);

    size_t sens2_bytes = (size_t)B_SZ * T_STEPS * U2 * 4;
    size_t sens1_bytes = (size_t)B_SZ * T_STEPS * U1 * 4;
    bool hoist2 = (off + 2 * sens2_bytes + 512) <= ws_size;
    float* sn2 = nullptr; float* sd2 = nullptr;
    if (hoist2) {
        sn2 = (float*)alloc(sens2_bytes);
        sd2 = (float*)alloc(sens2_bytes);
    }
    bool hoist1 = (off + 2 * sens1_bytes + 512) <= ws_size;
    float* sn1 = nullptr; float* sd1 = nullptr;
    if (hoist1) {
        sn1 = (float*)alloc(sens1_bytes);
        sd1 = (float*)alloc(sens1_bytes);
    }

    prep_ilv<<<((S1/4)*U1 + 255)/256, 256, 0, stream>>>(l1_ss, l1_smu, l1_sw, l1_se, ABsI1, WsI1, S1/4, U1, 4, 8);
    prep_ilv<<<((U1/4)*U1 + 255)/256, 256, 0, stream>>>(l1_sg, l1_mu,  l1_w,  l1_er, ABrI1, WrI1, U1/4, U1, 4, 8);
    prep_ilv<<<((S2/4)*U2 + 255)/256, 256, 0, stream>>>(l2_ss, l2_smu, l2_sw, l2_se, ABsI2, WsI2, S2/4, U2, 8, 4);
    prep_ilv<<<((U2/4)*U2 + 255)/256, 256, 0, stream>>>(l2_sg, l2_mu,  l2_w,  l2_er, ABrI2, WrI2, U2/4, U2, 16, 4);
    prep_half<<<(S1 * U1 + 255)/256, 256, 0, stream>>>(l1_ss, l1_smu, l1_sw, l1_se, AB1s, W1s, S1 * U1);
    prep_half<<<(S2 * U2 + 255)/256, 256, 0, stream>>>(l2_ss, l2_smu, l2_sw, l2_se, AB2s, W2s, S2 * U2);
    prep_vec<<<1, 256, 0, stream>>>(l1_gl, l1_vl, l1_cm, cmt1, nb1, db1, U1);
    prep_vec<<<1, 256, 0, stream>>>(l2_gl, l2_vl, l2_cm, cmt2, nb2, db2, U2);

    if (hoist1) {
        sens1k<<<B_SZ * (T_STEPS / 8), 256, 0, stream>>>(x, l1_iw, l1_ib, AB1s, W1s, sn1, sd1);
        ltc1<true><<<B_SZ, 1024, 0, stream>>>(x, l1_iw, l1_ib, ABsI1, WsI1, ABrI1, WrI1,
                                              sn1, sd1, cmt1, nb1, db1, l1_ow, l1_ob, h1);
    } else {
        ltc1<false><<<B_SZ, 1024, 0, stream>>>(x, l1_iw, l1_ib, ABsI1, WsI1, ABrI1, WrI1,
                                               nullptr, nullptr, cmt1, nb1, db1, l1_ow, l1_ob, h1);
    }

    if (hoist2) {
        sens2k<<<B_SZ * (T_STEPS / 4), 256, 0, stream>>>(h1, l2_iw, l2_ib, AB2s, W2s, sn2, sd2);
        ltc2<true><<<B_SZ, 1024, 0, stream>>>(h1, l2_iw, l2_ib, ABsI2, WsI2, ABrI2, WrI2,
                                              sn2, sd2, cmt2, nb2, db2, l2_ow, l2_ob, h2);
    } else {
        ltc2<false><<<B_SZ, 1024, 0, stream>>>(h1, l2_iw, l2_ib, ABsI2, WsI2, ABrI2, WrI2,
                                               nullptr, nullptr, cmt2, nb2, db2, l2_ow, l2_ob, h2);
    }
    fc_head<<<B_SZ * T_STEPS / 8, 512, 0, stream>>>(h2, fcw, fcb, (float*)d_out);
}

// Round 14
// 18112.175 us; speedup vs baseline: 1.0712x; 1.0712x over previous
//
#include <hip/hip_runtime.h>
#include <hip/hip_fp16.h>

#define B_SZ    64
#define T_STEPS 512
#define U1      128
#define S1      128
#define U2      256
#define S2      128
#define NUNF    6
#define RC2     6       // ltc2: LDS-resident chunks (of 16) per group

typedef _Float16 h2f __attribute__((ext_vector_type(2)));

__device__ __forceinline__ float fast_exp2(float x) { return __builtin_amdgcn_exp2f(x); }
__device__ __forceinline__ float fast_rcp(float x)  { return __builtin_amdgcn_rcpf(x); }
__device__ __forceinline__ h2f u2h(unsigned u) { union { unsigned x; h2f h; } c; c.x = u; return c.h; }
__device__ __forceinline__ h2f pkrtz(float a, float b)
{
    return __builtin_bit_cast(h2f, __builtin_amdgcn_cvt_pkrtz(a, b));
}
template <typename T, typename F>
__device__ __forceinline__ T bitc(F f)
{
    static_assert(sizeof(T) == sizeof(F), "size mismatch");
    T t; __builtin_memcpy(&t, &f, sizeof(T)); return t;
}

// ---------------------------------------------------------------------------
// eval4d (fp32-trans path, r12 form — ltc1): AB half2(A,B)/pair, W half.
// sigmoid((v-mu)*sig) = 1/(1+exp2(B-A*v)); |W| = w*mask (w>0).
// ---------------------------------------------------------------------------
__device__ __forceinline__ void eval4d(uint4 ab4, uint2 w2, float4 vv,
                                       float& an, float& ad)
{
    h2f ab0 = u2h(ab4.x), ab1 = u2h(ab4.y), ab2 = u2h(ab4.z), ab3 = u2h(ab4.w);
    float r0 = fast_rcp(1.f + fast_exp2(fmaf(-(float)ab0[0], vv.x, (float)ab0[1])));
    float r1 = fast_rcp(1.f + fast_exp2(fmaf(-(float)ab1[0], vv.y, (float)ab1[1])));
    float r2 = fast_rcp(1.f + fast_exp2(fmaf(-(float)ab2[0], vv.z, (float)ab2[1])));
    float r3 = fast_rcp(1.f + fast_exp2(fmaf(-(float)ab3[0], vv.w, (float)ab3[1])));
    h2f rp01 = pkrtz(r0, r1);
    h2f rp23 = pkrtz(r2, r3);
    an = __builtin_amdgcn_fdot2(u2h(w2.x), rp01, an, false);
    an = __builtin_amdgcn_fdot2(u2h(w2.y), rp23, an, false);
    ad = __builtin_amdgcn_fdot2(u2h(w2.x & 0x7FFF7FFFu), rp01, ad, false);
    ad = __builtin_amdgcn_fdot2(u2h(w2.y & 0x7FFF7FFFu), rp23, ad, false);
}

// ---------------------------------------------------------------------------
// eval16 (packed fp16 path — ltc2): P = {An01, An23, B01, B23} (An = -A),
// w2 = {W01, W23}, v01/v23 = half2 row pairs.  10 VALU + 8 trans per 4 pairs.
// ---------------------------------------------------------------------------
__device__ __forceinline__ void eval16(uint4 P, uint2 w2, unsigned v01, unsigned v23,
                                       float& an, float& ad)
{
    const __half2 one2 = __float2half2_rn(1.0f);
    __half2 arg01 = __hfma2(bitc<__half2>(P.x), bitc<__half2>(v01), bitc<__half2>(P.z));
    __half2 arg23 = __hfma2(bitc<__half2>(P.y), bitc<__half2>(v23), bitc<__half2>(P.w));
    __half2 d01 = __hadd2(h2exp2(arg01), one2);
    __half2 d23 = __hadd2(h2exp2(arg23), one2);
    h2f r01 = bitc<h2f>(h2rcp(d01));
    h2f r23 = bitc<h2f>(h2rcp(d23));
    an = __builtin_amdgcn_fdot2(u2h(w2.x), r01, an, false);
    an = __builtin_amdgcn_fdot2(u2h(w2.y), r23, an, false);
    ad = __builtin_amdgcn_fdot2(u2h(w2.x & 0x7FFF7FFFu), r01, ad, false);
    ad = __builtin_amdgcn_fdot2(u2h(w2.y & 0x7FFF7FFFu), r23, ad, false);
}

// ---------------------------------------------------------------------------
// prep: interleaved [c][u][g], AB = half2(A,B) per pair (eval4d format, ltc1)
// ---------------------------------------------------------------------------
__global__ void prep_ilv(const float* __restrict__ sg, const float* __restrict__ mu,
                         const float* __restrict__ w, const float* __restrict__ er,
                         uint4* __restrict__ ABI, uint2* __restrict__ WI,
                         int S4, int U, int CPG, int NG)
{
    int i = blockIdx.x * 256 + threadIdx.x;
    if (i >= S4 * U) return;
    int uo = i % U, s4 = i / U;
    int g = s4 / CPG, c = s4 % CPG;
    const float L2E = 1.4426950408889634f;
    unsigned ab[4]; __half wh[4];
    #pragma unroll
    for (int q = 0; q < 4; ++q) {
        size_t idx = (size_t)(s4 * 4 + q) * U + uo;
        float a = sg[idx] * L2E;
        __half2 h = __floats2half2_rn(a, mu[idx] * a);
        ab[q] = bitc<unsigned>(h);
        wh[q] = __float2half_rn(w[idx] * er[idx]);
    }
    __half2 w01 = __halves2half2(wh[0], wh[1]);
    __half2 w23 = __halves2half2(wh[2], wh[3]);
    int o = (c * U + uo) * NG + g;
    ABI[o] = make_uint4(ab[0], ab[1], ab[2], ab[3]);
    WI[o]  = make_uint2(bitc<unsigned>(w01), bitc<unsigned>(w23));
}

// ---------------------------------------------------------------------------
// prep: interleaved [c][u][g], P = {An01,An23,B01,B23} (eval16 format, ltc2)
// ---------------------------------------------------------------------------
__global__ void prep_ilv16(const float* __restrict__ sg, const float* __restrict__ mu,
                           const float* __restrict__ w, const float* __restrict__ er,
                           uint4* __restrict__ P, uint2* __restrict__ WI,
                           int S4, int U, int CPG, int NG)
{
    int i = blockIdx.x * 256 + threadIdx.x;
    if (i >= S4 * U) return;
    int uo = i % U, s4 = i / U;
    int g = s4 / CPG, c = s4 % CPG;
    const float L2E = 1.4426950408889634f;
    float An[4], Bq[4]; __half wh[4];
    #pragma unroll
    for (int q = 0; q < 4; ++q) {
        size_t idx = (size_t)(s4 * 4 + q) * U + uo;
        float a = sg[idx] * L2E;
        An[q] = -a;
        Bq[q] = mu[idx] * a;
        wh[q] = __float2half_rn(w[idx] * er[idx]);
    }
    unsigned an01 = bitc<unsigned>(__floats2half2_rn(An[0], An[1]));
    unsigned an23 = bitc<unsigned>(__floats2half2_rn(An[2], An[3]));
    unsigned b01  = bitc<unsigned>(__floats2half2_rn(Bq[0], Bq[1]));
    unsigned b23  = bitc<unsigned>(__floats2half2_rn(Bq[2], Bq[3]));
    __half2 w01 = __halves2half2(wh[0], wh[1]);
    __half2 w23 = __halves2half2(wh[2], wh[3]);
    int o = (c * U + uo) * NG + g;
    P[o]  = make_uint4(an01, an23, b01, b23);
    WI[o] = make_uint2(bitc<unsigned>(w01), bitc<unsigned>(w23));
}

// linear fp16 pack (sens1k / sens2k)
__global__ void prep_half(const float* __restrict__ sg, const float* __restrict__ mu,
                          const float* __restrict__ w, const float* __restrict__ er,
                          __half2* __restrict__ AB, __half* __restrict__ W, int n)
{
    int i = blockIdx.x * 256 + threadIdx.x;
    if (i >= n) return;
    const float L2E = 1.4426950408889634f;
    float a = sg[i] * L2E;
    AB[i] = __floats2half2_rn(a, mu[i] * a);
    W[i]  = __float2half_rn(w[i] * er[i]);
}

__global__ void prep_vec(const float* __restrict__ gleak, const float* __restrict__ vleak,
                         const float* __restrict__ cm,
                         float* __restrict__ cmt, float* __restrict__ nb,
                         float* __restrict__ db, int n)
{
    int i = blockIdx.x * 256 + threadIdx.x;
    if (i >= n) return;
    float c6 = cm[i] * 6.f;
    float gl = gleak[i];
    cmt[i] = c6;
    nb[i]  = gl * vleak[i];
    db[i]  = c6 + gl + 1e-8f;
}

// ---------------------------------------------------------------------------
// Layer-1 sensory sums, fully parallel over (b,t).
// ---------------------------------------------------------------------------
__global__ __launch_bounds__(256, 4) void sens1k(
    const float* __restrict__ x,
    const float* __restrict__ in_w, const float* __restrict__ in_b,
    const __half2* __restrict__ ABs, const __half* __restrict__ Ws,
    float* __restrict__ sn, float* __restrict__ sd)
{
    const int tid = threadIdx.x;
    const int b   = blockIdx.x >> 6;
    const int t0  = (blockIdx.x & 63) << 3;
    const int u   = tid & 127;
    const int hf  = tid >> 7;

    __shared__ float ibu[8][S1];
    for (int idx = tid; idx < 8 * S1; idx += 256) {
        int tt = idx >> 7, s = idx & (S1 - 1);
        ibu[tt][s] = fmaf(x[((size_t)b * T_STEPS + t0 + tt) * S1 + s], in_w[s], in_b[s]);
    }
    __syncthreads();

    float an0 = 0, an1 = 0, an2 = 0, an3 = 0;
    float ad0 = 0, ad1 = 0, ad2 = 0, ad3 = 0;
    const int tb = hf * 4;
    for (int s = 0; s < S1; ++s) {
        __half2 ab = ABs[(size_t)s * U1 + u];
        float a  = __low2float(ab);
        float bb = __high2float(ab);
        float ww = __half2float(Ws[(size_t)s * U1 + u]);
        float aw = fabsf(ww);
        float r0 = fast_rcp(1.f + fast_exp2(fmaf(-a, ibu[tb + 0][s], bb)));
        float r1 = fast_rcp(1.f + fast_exp2(fmaf(-a, ibu[tb + 1][s], bb)));
        float r2 = fast_rcp(1.f + fast_exp2(fmaf(-a, ibu[tb + 2][s], bb)));
        float r3 = fast_rcp(1.f + fast_exp2(fmaf(-a, ibu[tb + 3][s], bb)));
        an0 = fmaf(ww, r0, an0); ad0 = fmaf(aw, r0, ad0);
        an1 = fmaf(ww, r1, an1); ad1 = fmaf(aw, r1, ad1);
        an2 = fmaf(ww, r2, an2); ad2 = fmaf(aw, r2, ad2);
        an3 = fmaf(ww, r3, an3); ad3 = fmaf(aw, r3, ad3);
    }
    size_t base = ((size_t)b * T_STEPS + t0 + tb) * U1 + u;
    sn[base]          = an0; sd[base]          = ad0;
    sn[base + U1]     = an1; sd[base + U1]     = ad1;
    sn[base + 2 * U1] = an2; sd[base + 2 * U1] = ad2;
    sn[base + 3 * U1] = an3; sd[base + 3 * U1] = ad3;
}

// ---------------------------------------------------------------------------
// Layer 1, butterfly (r12 structure, fp32-trans eval).
// ---------------------------------------------------------------------------
template <bool HOIST1>
__global__ __launch_bounds__(1024, 1) void ltc1(
    const float* __restrict__ x,
    const float* __restrict__ in_w, const float* __restrict__ in_b,
    const uint4* __restrict__ ABsI, const uint2* __restrict__ WsI,
    const uint4* __restrict__ ABrI, const uint2* __restrict__ WrI,
    const float* __restrict__ sn, const float* __restrict__ sd,
    const float* __restrict__ cmt, const float* __restrict__ nbv, const float* __restrict__ dbv,
    const float* __restrict__ ow, const float* __restrict__ ob,
    float* __restrict__ h1)
{
    const int b    = blockIdx.x;
    const int tid  = threadIdx.x;
    const int w    = tid >> 6;
    const int lane = tid & 63;
    const int g    = lane & 7;
    const int ul   = lane >> 3;
    const int u    = w * 8 + ul;

    __shared__ uint4 ABl[4 * 1024];
    __shared__ uint2 Wl[4 * 1024];
    __shared__ float vbuf[2][8][20];
    __shared__ float ibuf[S1];

    for (int idx = tid; idx < 4 * 1024; idx += 1024) {
        ABl[idx] = ABrI[idx];
        Wl[idx]  = WrI[idx];
    }
    for (int idx = tid; idx < 2 * 8 * 20; idx += 1024)
        (&vbuf[0][0][0])[idx] = 0.f;

    float v_reg = 0.f;
    const float c_cmt = cmt[u], c_nb = nbv[u], c_db = dbv[u];
    const float c_ow = ow[u], c_ob = ob[u];
    float c_iw = 0.f, c_ib = 0.f;
    if (!HOIST1 && tid < S1) { c_iw = in_w[tid]; c_ib = in_b[tid]; }

    const float* xb = x  + (size_t)b * T_STEPS * S1;
    float*       hb = h1 + (size_t)b * T_STEPS * U1;
    const uint4* pABs = ABsI + tid;
    const uint2* pWs  = WsI  + tid;

    __syncthreads();
    int buf = 0;

    float pf_n = 0.f, pf_d = 0.f;
    if (HOIST1) {
        size_t ro = ((size_t)b * T_STEPS) * U1 + u;
        pf_n = sn[ro]; pf_d = sd[ro];
    }

    for (int t = 0; t < T_STEPS; ++t) {
        float nb_t, db_t;
        if (HOIST1) {
            nb_t = c_nb + pf_n;
            db_t = c_db + pf_d;
            if (t + 1 < T_STEPS) {
                size_t ro = ((size_t)b * T_STEPS + t + 1) * U1 + u;
                pf_n = sn[ro]; pf_d = sd[ro];
            }
        } else {
            if (tid < S1) ibuf[tid] = fmaf(xb[(size_t)t * S1 + tid], c_iw, c_ib);
            __syncthreads();
            float an = 0.f, ad = 0.f;
            #pragma unroll
            for (int c = 0; c < 4; ++c) {
                uint4 ab = pABs[c * 1024];
                uint2 w2 = pWs[c * 1024];
                float4 vv = *reinterpret_cast<const float4*>(&ibuf[g * 16 + c * 4]);
                eval4d(ab, w2, vv, an, ad);
            }
            an += __shfl_xor(an, 1, 64); ad += __shfl_xor(ad, 1, 64);
            an += __shfl_xor(an, 2, 64); ad += __shfl_xor(ad, 2, 64);
            an += __shfl_xor(an, 4, 64); ad += __shfl_xor(ad, 4, 64);
            nb_t = c_nb + an; db_t = c_db + ad;
        }

        #pragma unroll 1
        for (int k = 0; k < NUNF; ++k) {
            float an = 0.f, ad = 0.f;
            const float* vb = &vbuf[buf][g][0];
            #pragma unroll
            for (int c = 0; c < 4; ++c) {
                uint4 ab = ABl[c * 1024 + tid];
                uint2 w2 = Wl[c * 1024 + tid];
                float4 vv = *reinterpret_cast<const float4*>(&vb[c * 4]);
                eval4d(ab, w2, vv, an, ad);
            }
            an += __shfl_xor(an, 1, 64); ad += __shfl_xor(ad, 1, 64);
            an += __shfl_xor(an, 2, 64); ad += __shfl_xor(ad, 2, 64);
            an += __shfl_xor(an, 4, 64); ad += __shfl_xor(ad, 4, 64);
            float wn = nb_t + an;
            float wd = db_t + ad;
            v_reg = fmaf(c_cmt, v_reg, wn) * fast_rcp(wd);
            if (g == 0) vbuf[buf ^ 1][w >> 1][(w & 1) * 8 + ul] = v_reg;
            buf ^= 1;
            __syncthreads();
        }
        if (g == 0) hb[(size_t)t * U1 + u] = fmaf(v_reg, c_ow, c_ob);
    }
}

// ---------------------------------------------------------------------------
// Layer-2 sensory sums, fully parallel over (b,t).
// ---------------------------------------------------------------------------
__global__ __launch_bounds__(256, 4) void sens2k(
    const float* __restrict__ h1,
    const float* __restrict__ in_w, const float* __restrict__ in_b,
    const __half2* __restrict__ ABs, const __half* __restrict__ Ws,
    float* __restrict__ sn, float* __restrict__ sd)
{
    const int tid = threadIdx.x;
    const int b   = blockIdx.x >> 7;
    const int t0  = (blockIdx.x & 127) << 2;

    __shared__ float ibu[4][S2];
    for (int idx = tid; idx < 4 * S2; idx += 256) {
        int tt = idx >> 7, s = idx & (S2 - 1);
        ibu[tt][s] = fmaf(h1[((size_t)b * T_STEPS + t0 + tt) * S2 + s], in_w[s], in_b[s]);
    }
    __syncthreads();

    const int u = tid;
    float an0 = 0, an1 = 0, an2 = 0, an3 = 0;
    float ad0 = 0, ad1 = 0, ad2 = 0, ad3 = 0;
    for (int s = 0; s < S2; ++s) {
        __half2 ab = ABs[(size_t)s * U2 + u];
        float a  = __low2float(ab);
        float bb = __high2float(ab);
        float ww = __half2float(Ws[(size_t)s * U2 + u]);
        float aw = fabsf(ww);
        float r0 = fast_rcp(1.f + fast_exp2(fmaf(-a, ibu[0][s], bb)));
        float r1 = fast_rcp(1.f + fast_exp2(fmaf(-a, ibu[1][s], bb)));
        float r2 = fast_rcp(1.f + fast_exp2(fmaf(-a, ibu[2][s], bb)));
        float r3 = fast_rcp(1.f + fast_exp2(fmaf(-a, ibu[3][s], bb)));
        an0 = fmaf(ww, r0, an0); ad0 = fmaf(aw, r0, ad0);
        an1 = fmaf(ww, r1, an1); ad1 = fmaf(aw, r1, ad1);
        an2 = fmaf(ww, r2, an2); ad2 = fmaf(aw, r2, ad2);
        an3 = fmaf(ww, r3, an3); ad3 = fmaf(aw, r3, ad3);
    }
    size_t base = ((size_t)b * T_STEPS + t0) * U2 + u;
    sn[base]          = an0; sd[base]          = ad0;
    sn[base + U2]     = an1; sd[base + U2]     = ad1;
    sn[base + 2 * U2] = an2; sd[base + 2 * U2] = ad2;
    sn[base + 3 * U2] = an3; sd[base + 3 * U2] = ad3;
}

// ---------------------------------------------------------------------------
// Layer 2, butterfly + packed-fp16 eval.  v broadcast in half2 (vbuf2):
// copy j holds rows j*64..j*64+63 as 32 half2 entries.
// ---------------------------------------------------------------------------
template <bool HOIST>
__global__ __launch_bounds__(1024, 1) void ltc2(
    const float* __restrict__ h1,
    const float* __restrict__ in_w, const float* __restrict__ in_b,
    const uint4* __restrict__ ABsI, const uint2* __restrict__ WsI,
    const uint4* __restrict__ ABrI, const uint2* __restrict__ WrI,
    const float* __restrict__ sn, const float* __restrict__ sd,
    const float* __restrict__ cmt, const float* __restrict__ nbv, const float* __restrict__ dbv,
    const float* __restrict__ ow, const float* __restrict__ ob,
    float* __restrict__ h2)
{
    const int b    = blockIdx.x;
    const int tid  = threadIdx.x;
    const int w    = tid >> 6;
    const int lane = tid & 63;
    const int g    = lane & 3;
    const int ul   = lane >> 2;
    const int u    = w * 16 + ul;

    __shared__ uint4    ABl[RC2 * U2 * 4];      // 98304 B
    __shared__ uint2    Wl[RC2 * U2 * 4];       // 49152 B
    __shared__ unsigned vbuf2[2][4][40];        // dbuf x 4 row-partitions x 32 half2 (+pad)
    __shared__ float    ibuf[S2];

    for (int idx = tid; idx < RC2 * U2 * 4; idx += 1024) {
        ABl[idx] = ABrI[idx];
        Wl[idx]  = WrI[idx];
    }
    for (int idx = tid; idx < 2 * 4 * 40; idx += 1024)
        (&vbuf2[0][0][0])[idx] = 0u;

    const uint4* pABr = ABrI + u * 4 + g;
    const uint2* pWr  = WrI  + u * 4 + g;
    const uint4* pABs = ABsI + u * 4 + g;
    const uint2* pWs  = WsI  + u * 4 + g;

    float v_reg = 0.f;
    const float c_cmt = cmt[u], c_nb = nbv[u], c_db = dbv[u];
    float c_ow = 0.f, c_ob = 0.f;
    if (u < 64) { c_ow = ow[u]; c_ob = ob[u]; }
    float c_iw = 0.f, c_ib = 0.f;
    if (!HOIST && tid < S2) { c_iw = in_w[tid]; c_ib = in_b[tid]; }

    const float* hb = h1 + (size_t)b * T_STEPS * S2;
    float*       op = h2 + (size_t)b * T_STEPS * 64;

    __syncthreads();
    int buf = 0;

    float pf_n = 0.f, pf_d = 0.f;
    if (HOIST) {
        size_t ro = ((size_t)b * T_STEPS) * U2 + u;
        pf_n = sn[ro]; pf_d = sd[ro];
    }

    for (int t = 0; t < T_STEPS; ++t) {
        float nb_t, db_t;
        if (HOIST) {
            nb_t = c_nb + pf_n;
            db_t = c_db + pf_d;
            if (t + 1 < T_STEPS) {
                size_t ro = ((size_t)b * T_STEPS + t + 1) * U2 + u;
                pf_n = sn[ro]; pf_d = sd[ro];
            }
        } else {
            if (tid < S2) ibuf[tid] = fmaf(hb[(size_t)t * S2 + tid], c_iw, c_ib);
            __syncthreads();
            float an = 0.f, ad = 0.f;
            #pragma unroll 2
            for (int c = 0; c < 8; ++c) {
                uint4 P  = pABs[c * 1024];
                uint2 w2 = pWs[c * 1024];
                float4 iv = *reinterpret_cast<const float4*>(&ibuf[g * 32 + c * 4]);
                unsigned v01 = bitc<unsigned>(pkrtz(iv.x, iv.y));
                unsigned v23 = bitc<unsigned>(pkrtz(iv.z, iv.w));
                eval16(P, w2, v01, v23, an, ad);
            }
            an += __shfl_xor(an, 1, 64); ad += __shfl_xor(ad, 1, 64);
            an += __shfl_xor(an, 2, 64); ad += __shfl_xor(ad, 2, 64);
            nb_t = c_nb + an; db_t = c_db + ad;
        }

        #pragma unroll 1
        for (int k = 0; k < NUNF; ++k) {
            float an = 0.f, ad = 0.f;
            const unsigned* vb = &vbuf2[buf][g][0];
            // LDS-resident chunk pairs (uint4 = v-pairs for 2 chunks)
            #pragma unroll
            for (int cc = 0; cc < RC2 / 2; ++cc) {
                uint4 vv = *reinterpret_cast<const uint4*>(&vb[4 * cc]);
                eval16(ABl[(2 * cc) * 1024 + tid],     Wl[(2 * cc) * 1024 + tid],     vv.x, vv.y, an, ad);
                eval16(ABl[(2 * cc + 1) * 1024 + tid], Wl[(2 * cc + 1) * 1024 + tid], vv.z, vv.w, an, ad);
            }
            // streamed chunk pairs
            #pragma unroll 2
            for (int cc = RC2 / 2; cc < 8; ++cc) {
                uint4 vv = *reinterpret_cast<const uint4*>(&vb[4 * cc]);
                eval16(pABr[(size_t)(2 * cc) * 1024],     pWr[(size_t)(2 * cc) * 1024],     vv.x, vv.y, an, ad);
                eval16(pABr[(size_t)(2 * cc + 1) * 1024], pWr[(size_t)(2 * cc + 1) * 1024], vv.z, vv.w, an, ad);
            }
            an += __shfl_xor(an, 1, 64); ad += __shfl_xor(ad, 1, 64);
            an += __shfl_xor(an, 2, 64); ad += __shfl_xor(ad, 2, 64);
            float wn = nb_t + an;
            float wd = db_t + ad;
            v_reg = fmaf(c_cmt, v_reg, wn) * fast_rcp(wd);
            float v_nx = __shfl_down(v_reg, 4, 64);     // column u+1's value
            if (g == 0 && !(ul & 1))
                vbuf2[buf ^ 1][w >> 2][(w & 3) * 8 + (ul >> 1)] =
                    bitc<unsigned>(pkrtz(v_reg, v_nx));
            buf ^= 1;
            __syncthreads();
        }
        if (u < 64 && g == 0) op[(size_t)t * 64 + u] = fmaf(v_reg, c_ow, c_ob);
    }
}

// ---------------------------------------------------------------------------
// FC head: out[b,t,o] = fcb[o] + sum_k h2[b,t,k] * fcw[o,k]
// ---------------------------------------------------------------------------
__global__ __launch_bounds__(512, 1) void fc_head(
    const float* __restrict__ h2, const float* __restrict__ fcw,
    const float* __restrict__ fcb, float* __restrict__ out)
{
    __shared__ float fwT[64 * 64];
    __shared__ float hs[8 * 64];
    const int tid = threadIdx.x;
    for (int i = tid; i < 64 * 64; i += 512) {
        int o = i >> 6, k = i & 63;
        fwT[k * 64 + o] = fcw[i];
    }
    size_t base = (size_t)blockIdx.x * 8 * 64;
    hs[tid] = h2[base + tid];
    __syncthreads();
    const int o = tid & 63, tt = tid >> 6;
    float acc = fcb[o];
    #pragma unroll
    for (int k = 0; k < 64; ++k)
        acc = fmaf(hs[tt * 64 + k], fwT[k * 64 + o], acc);
    out[base + tt * 64 + o] = acc;
}

// ---------------------------------------------------------------------------
extern "C" void kernel_launch(void* const* d_in, const int* in_sizes, int n_in,
                              void* d_out, int out_size, void* d_ws, size_t ws_size,
                              hipStream_t stream)
{
    (void)in_sizes; (void)n_in; (void)out_size;

    const float* x      = (const float*)d_in[0];
    const float* l1_iw  = (const float*)d_in[1];
    const float* l1_ib  = (const float*)d_in[2];
    const float* l1_sw  = (const float*)d_in[3];
    const float* l1_ss  = (const float*)d_in[4];
    const float* l1_smu = (const float*)d_in[5];
    const float* l1_se  = (const float*)d_in[6];
    const float* l1_w   = (const float*)d_in[8];
    const float* l1_sg  = (const float*)d_in[9];
    const float* l1_mu  = (const float*)d_in[10];
    const float* l1_er  = (const float*)d_in[11];
    const float* l1_gl  = (const float*)d_in[13];
    const float* l1_vl  = (const float*)d_in[14];
    const float* l1_cm  = (const float*)d_in[15];
    const float* l1_ow  = (const float*)d_in[16];
    const float* l1_ob  = (const float*)d_in[17];
    const float* l2_iw  = (const float*)d_in[18];
    const float* l2_ib  = (const float*)d_in[19];
    const float* l2_sw  = (const float*)d_in[20];
    const float* l2_ss  = (const float*)d_in[21];
    const float* l2_smu = (const float*)d_in[22];
    const float* l2_se  = (const float*)d_in[23];
    const float* l2_w   = (const float*)d_in[25];
    const float* l2_sg  = (const float*)d_in[26];
    const float* l2_mu  = (const float*)d_in[27];
    const float* l2_er  = (const float*)d_in[28];
    const float* l2_gl  = (const float*)d_in[30];
    const float* l2_vl  = (const float*)d_in[31];
    const float* l2_cm  = (const float*)d_in[32];
    const float* l2_ow  = (const float*)d_in[33];
    const float* l2_ob  = (const float*)d_in[34];
    const float* fcw    = (const float*)d_in[35];
    const float* fcb    = (const float*)d_in[36];

    char*  base = (char*)d_ws;
    size_t off  = 0;
    auto alloc = [&](size_t bytes) -> char* {
        char* p = base + off;
        off += (bytes + 255) & ~(size_t)255;
        return p;
    };

    float* h1 = (float*)alloc((size_t)B_SZ * T_STEPS * U1 * 4);
    float* h2 = (float*)alloc((size_t)B_SZ * T_STEPS * 64 * 4);
    uint4* ABsI1 = (uint4*)alloc((size_t)(S1 / 4) * U1 * 16);
    uint2* WsI1  = (uint2*)alloc((size_t)(S1 / 4) * U1 * 8);
    uint4* ABrI1 = (uint4*)alloc((size_t)(U1 / 4) * U1 * 16);
    uint2* WrI1  = (uint2*)alloc((size_t)(U1 / 4) * U1 * 8);
    uint4* ABsI2 = (uint4*)alloc((size_t)(S2 / 4) * U2 * 16);
    uint2* WsI2  = (uint2*)alloc((size_t)(S2 / 4) * U2 * 8);
    uint4* ABrI2 = (uint4*)alloc((size_t)(U2 / 4) * U2 * 16);
    uint2* WrI2  = (uint2*)alloc((size_t)(U2 / 4) * U2 * 8);
    __half2* AB1s = (__half2*)alloc((size_t)S1 * U1 * 4);
    __half*  W1s  = (__half*) alloc((size_t)S1 * U1 * 2);
    __half2* AB2s = (__half2*)alloc((size_t)S2 * U2 * 4);
    __half*  W2s  = (__half*) alloc((size_t)S2 * U2 * 2);
    float* cmt1 = (float*)alloc(U1 * 4);
    float* nb1  = (float*)alloc(U1 * 4);
    float* db1  = (float*)alloc(U1 * 4);
    float* cmt2 = (float*)alloc(U2 * 4);
    float* nb2  = (float*)alloc(U2 * 4);
    float* db2  = (float*)alloc(U2 * 4);

    size_t sens2_bytes = (size_t)B_SZ * T_STEPS * U2 * 4;
    size_t sens1_bytes = (size_t)B_SZ * T_STEPS * U1 * 4;
    bool hoist2 = (off + 2 * sens2_bytes + 512) <= ws_size;
    float* sn2 = nullptr; float* sd2 = nullptr;
    if (hoist2) {
        sn2 = (float*)alloc(sens2_bytes);
        sd2 = (float*)alloc(sens2_bytes);
    }
    bool hoist1 = (off + 2 * sens1_bytes + 512) <= ws_size;
    float* sn1 = nullptr; float* sd1 = nullptr;
    if (hoist1) {
        sn1 = (float*)alloc(sens1_bytes);
        sd1 = (float*)alloc(sens1_bytes);
    }

    // ltc1 params: eval4d format; ltc2 params: eval16 format
    prep_ilv<<<((S1/4)*U1 + 255)/256, 256, 0, stream>>>(l1_ss, l1_smu, l1_sw, l1_se, ABsI1, WsI1, S1/4, U1, 4, 8);
    prep_ilv<<<((U1/4)*U1 + 255)/256, 256, 0, stream>>>(l1_sg, l1_mu,  l1_w,  l1_er, ABrI1, WrI1, U1/4, U1, 4, 8);
    prep_ilv16<<<((S2/4)*U2 + 255)/256, 256, 0, stream>>>(l2_ss, l2_smu, l2_sw, l2_se, ABsI2, WsI2, S2/4, U2, 8, 4);
    prep_ilv16<<<((U2/4)*U2 + 255)/256, 256, 0, stream>>>(l2_sg, l2_mu,  l2_w,  l2_er, ABrI2, WrI2, U2/4, U2, 16, 4);
    prep_half<<<(S1 * U1 + 255)/256, 256, 0, stream>>>(l1_ss, l1_smu, l1_sw, l1_se, AB1s, W1s, S1 * U1);
    prep_half<<<(S2 * U2 + 255)/256, 256, 0, stream>>>(l2_ss, l2_smu, l2_sw, l2_se, AB2s, W2s, S2 * U2);
    prep_vec<<<1, 256, 0, stream>>>(l1_gl, l1_vl, l1_cm, cmt1, nb1, db1, U1);
    prep_vec<<<1, 256, 0, stream>>>(l2_gl, l2_vl, l2_cm, cmt2, nb2, db2, U2);

    if (hoist1) {
        sens1k<<<B_SZ * (T_STEPS / 8), 256, 0, stream>>>(x, l1_iw, l1_ib, AB1s, W1s, sn1, sd1);
        ltc1<true><<<B_SZ, 1024, 0, stream>>>(x, l1_iw, l1_ib, ABsI1, WsI1, ABrI1, WrI1,
                                              sn1, sd1, cmt1, nb1, db1, l1_ow, l1_ob, h1);
    } else {
        ltc1<false><<<B_SZ, 1024, 0, stream>>>(x, l1_iw, l1_ib, ABsI1, WsI1, ABrI1, WrI1,
                                               nullptr, nullptr, cmt1, nb1, db1, l1_ow, l1_ob, h1);
    }

    if (hoist2) {
        sens2k<<<B_SZ * (T_STEPS / 4), 256, 0, stream>>>(h1, l2_iw, l2_ib, AB2s, W2s, sn2, sd2);
        ltc2<true><<<B_SZ, 1024, 0, stream>>>(h1, l2_iw, l2_ib, ABsI2, WsI2, ABrI2, WrI2,
                                              sn2, sd2, cmt2, nb2, db2, l2_ow, l2_ob, h2);
    } else {
        ltc2<false><<<B_SZ, 1024, 0, stream>>>(h1, l2_iw, l2_ib, ABsI2, WsI2, ABrI2, WrI2,
                                               nullptr, nullptr, cmt2, nb2, db2, l2_ow, l2_ob, h2);
    }
    fc_head<<<B_SZ * T_STEPS / 8, 512, 0, stream>>>(h2, fcw, fcb, (float*)d_out);
}

// Round 15
// 14258.994 us; speedup vs baseline: 1.3607x; 1.2702x over previous
//
#include <hip/hip_runtime.h>
#include <hip/hip_fp16.h>

#define B_SZ    64
#define T_STEPS 512
#define U1      128
#define S1      128
#define U2      256
#define S2      128
#define NUNF    6
#define RC2     6       // ltc2: LDS-resident chunks (of 16) per group
#define SEG_T   32
#define NSEG    (T_STEPS / SEG_T)

typedef _Float16 h2f __attribute__((ext_vector_type(2)));

__device__ __forceinline__ float fast_exp2(float x) { return __builtin_amdgcn_exp2f(x); }
__device__ __forceinline__ float fast_rcp(float x)  { return __builtin_amdgcn_rcpf(x); }
__device__ __forceinline__ h2f u2h(unsigned u) { union { unsigned x; h2f h; } c; c.x = u; return c.h; }
__device__ __forceinline__ h2f pkrtz(float a, float b)
{
    return __builtin_bit_cast(h2f, __builtin_amdgcn_cvt_pkrtz(a, b));
}
template <typename T, typename F>
__device__ __forceinline__ T bitc(F f)
{
    static_assert(sizeof(T) == sizeof(F), "size mismatch");
    T t; __builtin_memcpy(&t, &f, sizeof(T)); return t;
}

// ---------------------------------------------------------------------------
// eval4d (fp32-trans, fp16-param): AB half2(A,B)/pair, W half.
// sigmoid((v-mu)*sig) = 1/(1+exp2(B-A*v)); |W| = w*mask (w>0).
// ---------------------------------------------------------------------------
__device__ __forceinline__ void eval4d(uint4 ab4, uint2 w2, float4 vv,
                                       float& an, float& ad)
{
    h2f ab0 = u2h(ab4.x), ab1 = u2h(ab4.y), ab2 = u2h(ab4.z), ab3 = u2h(ab4.w);
    float r0 = fast_rcp(1.f + fast_exp2(fmaf(-(float)ab0[0], vv.x, (float)ab0[1])));
    float r1 = fast_rcp(1.f + fast_exp2(fmaf(-(float)ab1[0], vv.y, (float)ab1[1])));
    float r2 = fast_rcp(1.f + fast_exp2(fmaf(-(float)ab2[0], vv.z, (float)ab2[1])));
    float r3 = fast_rcp(1.f + fast_exp2(fmaf(-(float)ab3[0], vv.w, (float)ab3[1])));
    h2f rp01 = pkrtz(r0, r1);
    h2f rp23 = pkrtz(r2, r3);
    an = __builtin_amdgcn_fdot2(u2h(w2.x), rp01, an, false);
    an = __builtin_amdgcn_fdot2(u2h(w2.y), rp23, an, false);
    ad = __builtin_amdgcn_fdot2(u2h(w2.x & 0x7FFF7FFFu), rp01, ad, false);
    ad = __builtin_amdgcn_fdot2(u2h(w2.y & 0x7FFF7FFFu), rp23, ad, false);
}

// ---------------------------------------------------------------------------
// eval16 (packed fp16 path — ltc2): P = {An01,An23,B01,B23} (An = -A).
// ---------------------------------------------------------------------------
__device__ __forceinline__ void eval16(uint4 P, uint2 w2, unsigned v01, unsigned v23,
                                       float& an, float& ad)
{
    const __half2 one2 = __float2half2_rn(1.0f);
    __half2 arg01 = __hfma2(bitc<__half2>(P.x), bitc<__half2>(v01), bitc<__half2>(P.z));
    __half2 arg23 = __hfma2(bitc<__half2>(P.y), bitc<__half2>(v23), bitc<__half2>(P.w));
    __half2 d01 = __hadd2(h2exp2(arg01), one2);
    __half2 d23 = __hadd2(h2exp2(arg23), one2);
    h2f r01 = bitc<h2f>(h2rcp(d01));
    h2f r23 = bitc<h2f>(h2rcp(d23));
    an = __builtin_amdgcn_fdot2(u2h(w2.x), r01, an, false);
    an = __builtin_amdgcn_fdot2(u2h(w2.y), r23, an, false);
    ad = __builtin_amdgcn_fdot2(u2h(w2.x & 0x7FFF7FFFu), r01, ad, false);
    ad = __builtin_amdgcn_fdot2(u2h(w2.y & 0x7FFF7FFFu), r23, ad, false);
}

// ---------------------------------------------------------------------------
// prep: interleaved [c][u][g], AB = half2(A,B) per pair (eval4d format)
// ---------------------------------------------------------------------------
__global__ void prep_ilv(const float* __restrict__ sg, const float* __restrict__ mu,
                         const float* __restrict__ w, const float* __restrict__ er,
                         uint4* __restrict__ ABI, uint2* __restrict__ WI,
                         int S4, int U, int CPG, int NG)
{
    int i = blockIdx.x * 256 + threadIdx.x;
    if (i >= S4 * U) return;
    int uo = i % U, s4 = i / U;
    int g = s4 / CPG, c = s4 % CPG;
    const float L2E = 1.4426950408889634f;
    unsigned ab[4]; __half wh[4];
    #pragma unroll
    for (int q = 0; q < 4; ++q) {
        size_t idx = (size_t)(s4 * 4 + q) * U + uo;
        float a = sg[idx] * L2E;
        __half2 h = __floats2half2_rn(a, mu[idx] * a);
        ab[q] = bitc<unsigned>(h);
        wh[q] = __float2half_rn(w[idx] * er[idx]);
    }
    __half2 w01 = __halves2half2(wh[0], wh[1]);
    __half2 w23 = __halves2half2(wh[2], wh[3]);
    int o = (c * U + uo) * NG + g;
    ABI[o] = make_uint4(ab[0], ab[1], ab[2], ab[3]);
    WI[o]  = make_uint2(bitc<unsigned>(w01), bitc<unsigned>(w23));
}

// ---------------------------------------------------------------------------
// prep: interleaved [c][u][g], P = {An01,An23,B01,B23} (eval16 format)
// ---------------------------------------------------------------------------
__global__ void prep_ilv16(const float* __restrict__ sg, const float* __restrict__ mu,
                           const float* __restrict__ w, const float* __restrict__ er,
                           uint4* __restrict__ P, uint2* __restrict__ WI,
                           int S4, int U, int CPG, int NG)
{
    int i = blockIdx.x * 256 + threadIdx.x;
    if (i >= S4 * U) return;
    int uo = i % U, s4 = i / U;
    int g = s4 / CPG, c = s4 % CPG;
    const float L2E = 1.4426950408889634f;
    float An[4], Bq[4]; __half wh[4];
    #pragma unroll
    for (int q = 0; q < 4; ++q) {
        size_t idx = (size_t)(s4 * 4 + q) * U + uo;
        float a = sg[idx] * L2E;
        An[q] = -a;
        Bq[q] = mu[idx] * a;
        wh[q] = __float2half_rn(w[idx] * er[idx]);
    }
    unsigned an01 = bitc<unsigned>(__floats2half2_rn(An[0], An[1]));
    unsigned an23 = bitc<unsigned>(__floats2half2_rn(An[2], An[3]));
    unsigned b01  = bitc<unsigned>(__floats2half2_rn(Bq[0], Bq[1]));
    unsigned b23  = bitc<unsigned>(__floats2half2_rn(Bq[2], Bq[3]));
    __half2 w01 = __halves2half2(wh[0], wh[1]);
    __half2 w23 = __halves2half2(wh[2], wh[3]);
    int o = (c * U + uo) * NG + g;
    P[o]  = make_uint4(an01, an23, b01, b23);
    WI[o] = make_uint2(bitc<unsigned>(w01), bitc<unsigned>(w23));
}

// linear fp16 pack (producer sens2 pass)
__global__ void prep_half(const float* __restrict__ sg, const float* __restrict__ mu,
                          const float* __restrict__ w, const float* __restrict__ er,
                          __half2* __restrict__ AB, __half* __restrict__ W, int n)
{
    int i = blockIdx.x * 256 + threadIdx.x;
    if (i >= n) return;
    const float L2E = 1.4426950408889634f;
    float a = sg[i] * L2E;
    AB[i] = __floats2half2_rn(a, mu[i] * a);
    W[i]  = __float2half_rn(w[i] * er[i]);
}

__global__ void prep_vec(const float* __restrict__ gleak, const float* __restrict__ vleak,
                         const float* __restrict__ cm,
                         float* __restrict__ cmt, float* __restrict__ nb,
                         float* __restrict__ db, int n)
{
    int i = blockIdx.x * 256 + threadIdx.x;
    if (i >= n) return;
    float c6 = cm[i] * 6.f;
    float gl = gleak[i];
    cmt[i] = c6;
    nb[i]  = gl * vleak[i];
    db[i]  = c6 + gl + 1e-8f;
}

// ---------------------------------------------------------------------------
// Fused pipeline: 128 blocks.
//   blocks 0..63  (producer): ltc1 (inline sens1) + per-segment sens2 sums,
//                 publishing flags[b][seg] with ONE agent-release per segment.
//   blocks 64..127 (consumer): ltc2-HOIST; relaxed-spin + ONE acquire/segment.
// Coarse sync (1024 events total) avoids round-3's per-step L2-flush disease.
// ---------------------------------------------------------------------------
__global__ __launch_bounds__(1024, 1) void ltc_pipe(
    const float* __restrict__ x,
    const float* __restrict__ iw1, const float* __restrict__ ib1,
    const uint4* __restrict__ ABsI1, const uint2* __restrict__ WsI1,
    const uint4* __restrict__ ABrI1, const uint2* __restrict__ WrI1,
    const float* __restrict__ cmt1, const float* __restrict__ nb1v, const float* __restrict__ db1v,
    const float* __restrict__ ow1, const float* __restrict__ ob1,
    const float* __restrict__ iw2, const float* __restrict__ ib2,
    const __half2* __restrict__ AB2s, const __half* __restrict__ W2sl,
    const uint4* __restrict__ ABrI2, const uint2* __restrict__ WrI2,
    const float* __restrict__ cmt2, const float* __restrict__ nb2v, const float* __restrict__ db2v,
    const float* __restrict__ ow2, const float* __restrict__ ob2,
    float* __restrict__ h1, float* __restrict__ h2,
    float* __restrict__ sn2, float* __restrict__ sd2,
    unsigned* flags)
{
    __shared__ __align__(16) char smem[148736];
    const int tid = threadIdx.x;

    if (blockIdx.x < 64) {
        // ------------------------------ producer ------------------------------
        const int b    = blockIdx.x;
        const int w    = tid >> 6;
        const int lane = tid & 63;
        const int g    = lane & 7;              // 8 groups x 16 rows
        const int ul   = lane >> 3;
        const int u    = w * 8 + ul;            // 128 columns

        uint4* ABl = (uint4*)smem;                                   // 64 KB
        uint2* Wl  = (uint2*)(smem + 65536);                         // 32 KB
        float (*vbuf)[8][20] = (float (*)[8][20])(smem + 98304);     // 1.25 KB
        float* ibuf = (float*)(smem + 99584);                        // 512 B
        float (*ibu)[S2] = (float (*)[S2])(smem + 100096);           // 16 KB

        for (int idx = tid; idx < 4 * 1024; idx += 1024) {
            ABl[idx] = ABrI1[idx];
            Wl[idx]  = WrI1[idx];
        }
        for (int idx = tid; idx < 2 * 8 * 20; idx += 1024)
            (&vbuf[0][0][0])[idx] = 0.f;

        float v_reg = 0.f;
        const float c_cmt = cmt1[u], c_nb = nb1v[u], c_db = db1v[u];
        const float c_ow = ow1[u], c_ob = ob1[u];
        float c_iw = 0.f, c_ib = 0.f;
        if (tid < S1) { c_iw = iw1[tid]; c_ib = ib1[tid]; }

        const float* xb = x  + (size_t)b * T_STEPS * S1;
        float*       hb = h1 + (size_t)b * T_STEPS * U1;
        const uint4* pABs = ABsI1 + tid;
        const uint2* pWs  = WsI1  + tid;

        __syncthreads();
        int buf = 0;

        for (int seg = 0; seg < NSEG; ++seg) {
            for (int ts = 0; ts < SEG_T; ++ts) {
                const int t = seg * SEG_T + ts;
                if (tid < S1) ibuf[tid] = fmaf(xb[(size_t)t * S1 + tid], c_iw, c_ib);
                __syncthreads();
                float an = 0.f, ad = 0.f;
                #pragma unroll
                for (int c = 0; c < 4; ++c) {
                    uint4 ab = pABs[c * 1024];
                    uint2 w2 = pWs[c * 1024];
                    float4 vv = *reinterpret_cast<const float4*>(&ibuf[g * 16 + c * 4]);
                    eval4d(ab, w2, vv, an, ad);
                }
                an += __shfl_xor(an, 1, 64); ad += __shfl_xor(ad, 1, 64);
                an += __shfl_xor(an, 2, 64); ad += __shfl_xor(ad, 2, 64);
                an += __shfl_xor(an, 4, 64); ad += __shfl_xor(ad, 4, 64);
                const float nb_t = c_nb + an, db_t = c_db + ad;

                #pragma unroll 1
                for (int k = 0; k < NUNF; ++k) {
                    float anu = 0.f, adu = 0.f;
                    const float* vb = &vbuf[buf][g][0];
                    #pragma unroll
                    for (int c = 0; c < 4; ++c) {
                        uint4 ab = ABl[c * 1024 + tid];
                        uint2 w2 = Wl[c * 1024 + tid];
                        float4 vv = *reinterpret_cast<const float4*>(&vb[c * 4]);
                        eval4d(ab, w2, vv, anu, adu);
                    }
                    anu += __shfl_xor(anu, 1, 64); adu += __shfl_xor(adu, 1, 64);
                    anu += __shfl_xor(anu, 2, 64); adu += __shfl_xor(adu, 2, 64);
                    anu += __shfl_xor(anu, 4, 64); adu += __shfl_xor(adu, 4, 64);
                    float wn = nb_t + anu;
                    float wd = db_t + adu;
                    v_reg = fmaf(c_cmt, v_reg, wn) * fast_rcp(wd);
                    if (g == 0) vbuf[buf ^ 1][w >> 1][(w & 1) * 8 + ul] = v_reg;
                    buf ^= 1;
                    __syncthreads();
                }
                if (g == 0) hb[(size_t)t * U1 + u] = fmaf(v_reg, c_ow, c_ob);
            }

            // ---- sens2 sums for this segment (producer slack) ----
            __syncthreads();    // drains h1 stores (vmcnt(0) before barrier)
            for (int idx = tid; idx < SEG_T * S2; idx += 1024) {
                int tt = idx >> 7, s = idx & (S2 - 1);
                ibu[tt][s] = fmaf(hb[(size_t)(seg * SEG_T + tt) * S2 + s], iw2[s], ib2[s]);
            }
            __syncthreads();
            {
                const int u2 = tid & 255, tg = tid >> 8;
                #pragma unroll
                for (int half = 0; half < 2; ++half) {
                    const int tb = tg * 8 + half * 4;
                    float an0 = 0, an1 = 0, an2 = 0, an3 = 0;
                    float ad0 = 0, ad1 = 0, ad2 = 0, ad3 = 0;
                    for (int s = 0; s < S2; ++s) {
                        __half2 ab = AB2s[(size_t)s * U2 + u2];
                        float a  = __low2float(ab);
                        float bb = __high2float(ab);
                        float ww = __half2float(W2sl[(size_t)s * U2 + u2]);
                        float aw = fabsf(ww);
                        float r0 = fast_rcp(1.f + fast_exp2(fmaf(-a, ibu[tb + 0][s], bb)));
                        float r1 = fast_rcp(1.f + fast_exp2(fmaf(-a, ibu[tb + 1][s], bb)));
                        float r2 = fast_rcp(1.f + fast_exp2(fmaf(-a, ibu[tb + 2][s], bb)));
                        float r3 = fast_rcp(1.f + fast_exp2(fmaf(-a, ibu[tb + 3][s], bb)));
                        an0 = fmaf(ww, r0, an0); ad0 = fmaf(aw, r0, ad0);
                        an1 = fmaf(ww, r1, an1); ad1 = fmaf(aw, r1, ad1);
                        an2 = fmaf(ww, r2, an2); ad2 = fmaf(aw, r2, ad2);
                        an3 = fmaf(ww, r3, an3); ad3 = fmaf(aw, r3, ad3);
                    }
                    size_t bo = ((size_t)b * T_STEPS + seg * SEG_T + tb) * U2 + u2;
                    sn2[bo]          = an0; sd2[bo]          = ad0;
                    sn2[bo + U2]     = an1; sd2[bo + U2]     = ad1;
                    sn2[bo + 2 * U2] = an2; sd2[bo + 2 * U2] = ad2;
                    sn2[bo + 3 * U2] = an3; sd2[bo + 3 * U2] = ad3;
                }
            }
            __syncthreads();    // drains sn/sd stores
            if (tid == 0)
                __hip_atomic_store(&flags[b * NSEG + seg], 1u,
                                   __ATOMIC_RELEASE, __HIP_MEMORY_SCOPE_AGENT);
        }
    } else {
        // ------------------------------ consumer ------------------------------
        const int b    = blockIdx.x - 64;
        const int w    = tid >> 6;
        const int lane = tid & 63;
        const int g    = lane & 3;
        const int ul   = lane >> 2;
        const int u    = w * 16 + ul;

        uint4* ABl = (uint4*)smem;                                       // 96 KB
        uint2* Wl  = (uint2*)(smem + 98304);                             // 48 KB
        unsigned (*vbuf)[4][40] = (unsigned (*)[4][40])(smem + 147456);  // 1.25 KB

        for (int idx = tid; idx < RC2 * U2 * 4; idx += 1024) {
            ABl[idx] = ABrI2[idx];
            Wl[idx]  = WrI2[idx];
        }
        for (int idx = tid; idx < 2 * 4 * 40; idx += 1024)
            (&vbuf[0][0][0])[idx] = 0u;

        const uint4* pABr = ABrI2 + u * 4 + g;
        const uint2* pWr  = WrI2  + u * 4 + g;

        float v_reg = 0.f;
        const float c_cmt = cmt2[u], c_nb = nb2v[u], c_db = db2v[u];
        float c_ow = 0.f, c_ob = 0.f;
        if (u < 64) { c_ow = ow2[u]; c_ob = ob2[u]; }

        float* op = h2 + (size_t)b * T_STEPS * 64;

        __syncthreads();
        int buf = 0;

        for (int seg = 0; seg < NSEG; ++seg) {
            if (tid == 0) {
                while (__hip_atomic_load(&flags[b * NSEG + seg],
                                         __ATOMIC_RELAXED, __HIP_MEMORY_SCOPE_AGENT) == 0u)
                    __builtin_amdgcn_s_sleep(8);
                // single acquire: invalidates L1/L2 so the block sees sn2/sd2
                (void)__hip_atomic_load(&flags[b * NSEG + seg],
                                        __ATOMIC_ACQUIRE, __HIP_MEMORY_SCOPE_AGENT);
            }
            __syncthreads();

            float pf_n, pf_d;
            {
                size_t ro = ((size_t)b * T_STEPS + seg * SEG_T) * U2 + u;
                pf_n = sn2[ro]; pf_d = sd2[ro];
            }

            for (int ts = 0; ts < SEG_T; ++ts) {
                const int t = seg * SEG_T + ts;
                const float nb_t = c_nb + pf_n;
                const float db_t = c_db + pf_d;
                if (ts + 1 < SEG_T) {
                    size_t ro = ((size_t)b * T_STEPS + t + 1) * U2 + u;
                    pf_n = sn2[ro]; pf_d = sd2[ro];
                }

                #pragma unroll 1
                for (int k = 0; k < NUNF; ++k) {
                    float an = 0.f, ad = 0.f;
                    const unsigned* vb = &vbuf[buf][g][0];
                    #pragma unroll
                    for (int cc = 0; cc < RC2 / 2; ++cc) {
                        uint4 vv = *reinterpret_cast<const uint4*>(&vb[4 * cc]);
                        eval16(ABl[(2 * cc) * 1024 + tid],     Wl[(2 * cc) * 1024 + tid],     vv.x, vv.y, an, ad);
                        eval16(ABl[(2 * cc + 1) * 1024 + tid], Wl[(2 * cc + 1) * 1024 + tid], vv.z, vv.w, an, ad);
                    }
                    #pragma unroll 2
                    for (int cc = RC2 / 2; cc < 8; ++cc) {
                        uint4 vv = *reinterpret_cast<const uint4*>(&vb[4 * cc]);
                        eval16(pABr[(size_t)(2 * cc) * 1024],     pWr[(size_t)(2 * cc) * 1024],     vv.x, vv.y, an, ad);
                        eval16(pABr[(size_t)(2 * cc + 1) * 1024], pWr[(size_t)(2 * cc + 1) * 1024], vv.z, vv.w, an, ad);
                    }
                    an += __shfl_xor(an, 1, 64); ad += __shfl_xor(ad, 1, 64);
                    an += __shfl_xor(an, 2, 64); ad += __shfl_xor(ad, 2, 64);
                    float wn = nb_t + an;
                    float wd = db_t + ad;
                    v_reg = fmaf(c_cmt, v_reg, wn) * fast_rcp(wd);
                    float v_nx = __shfl_down(v_reg, 4, 64);
                    if (g == 0 && !(ul & 1))
                        vbuf[buf ^ 1][w >> 2][(w & 3) * 8 + (ul >> 1)] =
                            bitc<unsigned>(pkrtz(v_reg, v_nx));
                    buf ^= 1;
                    __syncthreads();
                }
                if (u < 64 && g == 0) op[(size_t)t * 64 + u] = fmaf(v_reg, c_ow, c_ob);
            }
        }
    }
}

// ---------------------------------------------------------------------------
// FC head: out[b,t,o] = fcb[o] + sum_k h2[b,t,k] * fcw[o,k]
// ---------------------------------------------------------------------------
__global__ __launch_bounds__(512, 1) void fc_head(
    const float* __restrict__ h2, const float* __restrict__ fcw,
    const float* __restrict__ fcb, float* __restrict__ out)
{
    __shared__ float fwT[64 * 64];
    __shared__ float hs[8 * 64];
    const int tid = threadIdx.x;
    for (int i = tid; i < 64 * 64; i += 512) {
        int o = i >> 6, k = i & 63;
        fwT[k * 64 + o] = fcw[i];
    }
    size_t base = (size_t)blockIdx.x * 8 * 64;
    hs[tid] = h2[base + tid];
    __syncthreads();
    const int o = tid & 63, tt = tid >> 6;
    float acc = fcb[o];
    #pragma unroll
    for (int k = 0; k < 64; ++k)
        acc = fmaf(hs[tt * 64 + k], fwT[k * 64 + o], acc);
    out[base + tt * 64 + o] = acc;
}

// ---------------------------------------------------------------------------
extern "C" void kernel_launch(void* const* d_in, const int* in_sizes, int n_in,
                              void* d_out, int out_size, void* d_ws, size_t ws_size,
                              hipStream_t stream)
{
    (void)in_sizes; (void)n_in; (void)out_size; (void)ws_size;

    const float* x      = (const float*)d_in[0];
    const float* l1_iw  = (const float*)d_in[1];
    const float* l1_ib  = (const float*)d_in[2];
    const float* l1_sw  = (const float*)d_in[3];
    const float* l1_ss  = (const float*)d_in[4];
    const float* l1_smu = (const float*)d_in[5];
    const float* l1_se  = (const float*)d_in[6];
    const float* l1_w   = (const float*)d_in[8];
    const float* l1_sg  = (const float*)d_in[9];
    const float* l1_mu  = (const float*)d_in[10];
    const float* l1_er  = (const float*)d_in[11];
    const float* l1_gl  = (const float*)d_in[13];
    const float* l1_vl  = (const float*)d_in[14];
    const float* l1_cm  = (const float*)d_in[15];
    const float* l1_ow  = (const float*)d_in[16];
    const float* l1_ob  = (const float*)d_in[17];
    const float* l2_iw  = (const float*)d_in[18];
    const float* l2_ib  = (const float*)d_in[19];
    const float* l2_sw  = (const float*)d_in[20];
    const float* l2_ss  = (const float*)d_in[21];
    const float* l2_smu = (const float*)d_in[22];
    const float* l2_se  = (const float*)d_in[23];
    const float* l2_w   = (const float*)d_in[25];
    const float* l2_sg  = (const float*)d_in[26];
    const float* l2_mu  = (const float*)d_in[27];
    const float* l2_er  = (const float*)d_in[28];
    const float* l2_gl  = (const float*)d_in[30];
    const float* l2_vl  = (const float*)d_in[31];
    const float* l2_cm  = (const float*)d_in[32];
    const float* l2_ow  = (const float*)d_in[33];
    const float* l2_ob  = (const float*)d_in[34];
    const float* fcw    = (const float*)d_in[35];
    const float* fcb    = (const float*)d_in[36];

    char*  base = (char*)d_ws;
    size_t off  = 0;
    auto alloc = [&](size_t bytes) -> char* {
        char* p = base + off;
        off += (bytes + 255) & ~(size_t)255;
        return p;
    };

    float* h1 = (float*)alloc((size_t)B_SZ * T_STEPS * U1 * 4);
    float* h2 = (float*)alloc((size_t)B_SZ * T_STEPS * 64 * 4);
    // ltc1 interleaved params (8 groups)
    uint4* ABsI1 = (uint4*)alloc((size_t)(S1 / 4) * U1 * 16);
    uint2* WsI1  = (uint2*)alloc((size_t)(S1 / 4) * U1 * 8);
    uint4* ABrI1 = (uint4*)alloc((size_t)(U1 / 4) * U1 * 16);
    uint2* WrI1  = (uint2*)alloc((size_t)(U1 / 4) * U1 * 8);
    // ltc2 recurrent interleaved params (4 groups, eval16 format)
    uint4* ABrI2 = (uint4*)alloc((size_t)(U2 / 4) * U2 * 16);
    uint2* WrI2  = (uint2*)alloc((size_t)(U2 / 4) * U2 * 8);
    // ltc2 sensory linear fp16 (producer sens2 pass)
    __half2* AB2s = (__half2*)alloc((size_t)S2 * U2 * 4);
    __half*  W2s  = (__half*) alloc((size_t)S2 * U2 * 2);
    float* cmt1 = (float*)alloc(U1 * 4);
    float* nb1  = (float*)alloc(U1 * 4);
    float* db1  = (float*)alloc(U1 * 4);
    float* cmt2 = (float*)alloc(U2 * 4);
    float* nb2  = (float*)alloc(U2 * 4);
    float* db2  = (float*)alloc(U2 * 4);
    float* sn2  = (float*)alloc((size_t)B_SZ * T_STEPS * U2 * 4);
    float* sd2  = (float*)alloc((size_t)B_SZ * T_STEPS * U2 * 4);
    unsigned* flags = (unsigned*)alloc((size_t)B_SZ * NSEG * 4);

    // zero pipeline flags every call (graph-capturable)
    hipMemsetAsync(flags, 0, (size_t)B_SZ * NSEG * 4, stream);

    prep_ilv<<<((S1/4)*U1 + 255)/256, 256, 0, stream>>>(l1_ss, l1_smu, l1_sw, l1_se, ABsI1, WsI1, S1/4, U1, 4, 8);
    prep_ilv<<<((U1/4)*U1 + 255)/256, 256, 0, stream>>>(l1_sg, l1_mu,  l1_w,  l1_er, ABrI1, WrI1, U1/4, U1, 4, 8);
    prep_ilv16<<<((U2/4)*U2 + 255)/256, 256, 0, stream>>>(l2_sg, l2_mu, l2_w, l2_er, ABrI2, WrI2, U2/4, U2, 16, 4);
    prep_half<<<(S2 * U2 + 255)/256, 256, 0, stream>>>(l2_ss, l2_smu, l2_sw, l2_se, AB2s, W2s, S2 * U2);
    prep_vec<<<1, 256, 0, stream>>>(l1_gl, l1_vl, l1_cm, cmt1, nb1, db1, U1);
    prep_vec<<<1, 256, 0, stream>>>(l2_gl, l2_vl, l2_cm, cmt2, nb2, db2, U2);

    ltc_pipe<<<128, 1024, 0, stream>>>(
        x, l1_iw, l1_ib, ABsI1, WsI1, ABrI1, WrI1, cmt1, nb1, db1, l1_ow, l1_ob,
        l2_iw, l2_ib, AB2s, W2s, ABrI2, WrI2, cmt2, nb2, db2, l2_ow, l2_ob,
        h1, h2, sn2, sd2, flags);

    fc_head<<<B_SZ * T_STEPS / 8, 512, 0, stream>>>(h2, fcw, fcb, (float*)d_out);
}

// Round 16
// 11784.902 us; speedup vs baseline: 1.6463x; 1.2099x over previous
//
#include <hip/hip_runtime.h>
#include <hip/hip_fp16.h>

#define B_SZ    64
#define T_STEPS 512
#define U1      128
#define S1      128
#define U2      256
#define S2      128
#define NUNF    6
#define RC2     6       // ltc2: LDS-resident chunks (of 16) per group
#define NSTR    (16 - RC2)
#define SEG_T   32
#define NSEG    (T_STEPS / SEG_T)

typedef _Float16 h2f __attribute__((ext_vector_type(2)));

__device__ __forceinline__ float fast_exp2(float x) { return __builtin_amdgcn_exp2f(x); }
__device__ __forceinline__ float fast_rcp(float x)  { return __builtin_amdgcn_rcpf(x); }
__device__ __forceinline__ h2f u2h(unsigned u) { union { unsigned x; h2f h; } c; c.x = u; return c.h; }
__device__ __forceinline__ h2f pkrtz(float a, float b)
{
    return __builtin_bit_cast(h2f, __builtin_amdgcn_cvt_pkrtz(a, b));
}
template <typename T, typename F>
__device__ __forceinline__ T bitc(F f)
{
    static_assert(sizeof(T) == sizeof(F), "size mismatch");
    T t; __builtin_memcpy(&t, &f, sizeof(T)); return t;
}

// ---------------------------------------------------------------------------
// eval4d (fp32-trans, fp16-param): AB half2(A,B)/pair, W half.
// sigmoid((v-mu)*sig) = 1/(1+exp2(B-A*v)); |W| = w*mask (w>0).
// ---------------------------------------------------------------------------
__device__ __forceinline__ void eval4d(uint4 ab4, uint2 w2, float4 vv,
                                       float& an, float& ad)
{
    h2f ab0 = u2h(ab4.x), ab1 = u2h(ab4.y), ab2 = u2h(ab4.z), ab3 = u2h(ab4.w);
    float r0 = fast_rcp(1.f + fast_exp2(fmaf(-(float)ab0[0], vv.x, (float)ab0[1])));
    float r1 = fast_rcp(1.f + fast_exp2(fmaf(-(float)ab1[0], vv.y, (float)ab1[1])));
    float r2 = fast_rcp(1.f + fast_exp2(fmaf(-(float)ab2[0], vv.z, (float)ab2[1])));
    float r3 = fast_rcp(1.f + fast_exp2(fmaf(-(float)ab3[0], vv.w, (float)ab3[1])));
    h2f rp01 = pkrtz(r0, r1);
    h2f rp23 = pkrtz(r2, r3);
    an = __builtin_amdgcn_fdot2(u2h(w2.x), rp01, an, false);
    an = __builtin_amdgcn_fdot2(u2h(w2.y), rp23, an, false);
    ad = __builtin_amdgcn_fdot2(u2h(w2.x & 0x7FFF7FFFu), rp01, ad, false);
    ad = __builtin_amdgcn_fdot2(u2h(w2.y & 0x7FFF7FFFu), rp23, ad, false);
}

// ---------------------------------------------------------------------------
// eval16 (packed fp16 path — ltc2): P = {An01,An23,B01,B23} (An = -A).
// ---------------------------------------------------------------------------
__device__ __forceinline__ void eval16(uint4 P, uint2 w2, unsigned v01, unsigned v23,
                                       float& an, float& ad)
{
    const __half2 one2 = __float2half2_rn(1.0f);
    __half2 arg01 = __hfma2(bitc<__half2>(P.x), bitc<__half2>(v01), bitc<__half2>(P.z));
    __half2 arg23 = __hfma2(bitc<__half2>(P.y), bitc<__half2>(v23), bitc<__half2>(P.w));
    __half2 d01 = __hadd2(h2exp2(arg01), one2);
    __half2 d23 = __hadd2(h2exp2(arg23), one2);
    h2f r01 = bitc<h2f>(h2rcp(d01));
    h2f r23 = bitc<h2f>(h2rcp(d23));
    an = __builtin_amdgcn_fdot2(u2h(w2.x), r01, an, false);
    an = __builtin_amdgcn_fdot2(u2h(w2.y), r23, an, false);
    ad = __builtin_amdgcn_fdot2(u2h(w2.x & 0x7FFF7FFFu), r01, ad, false);
    ad = __builtin_amdgcn_fdot2(u2h(w2.y & 0x7FFF7FFFu), r23, ad, false);
}

// ---------------------------------------------------------------------------
// prep: interleaved [c][u][g], AB = half2(A,B) per pair (eval4d format)
// ---------------------------------------------------------------------------
__global__ void prep_ilv(const float* __restrict__ sg, const float* __restrict__ mu,
                         const float* __restrict__ w, const float* __restrict__ er,
                         uint4* __restrict__ ABI, uint2* __restrict__ WI,
                         int S4, int U, int CPG, int NG)
{
    int i = blockIdx.x * 256 + threadIdx.x;
    if (i >= S4 * U) return;
    int uo = i % U, s4 = i / U;
    int g = s4 / CPG, c = s4 % CPG;
    const float L2E = 1.4426950408889634f;
    unsigned ab[4]; __half wh[4];
    #pragma unroll
    for (int q = 0; q < 4; ++q) {
        size_t idx = (size_t)(s4 * 4 + q) * U + uo;
        float a = sg[idx] * L2E;
        __half2 h = __floats2half2_rn(a, mu[idx] * a);
        ab[q] = bitc<unsigned>(h);
        wh[q] = __float2half_rn(w[idx] * er[idx]);
    }
    __half2 w01 = __halves2half2(wh[0], wh[1]);
    __half2 w23 = __halves2half2(wh[2], wh[3]);
    int o = (c * U + uo) * NG + g;
    ABI[o] = make_uint4(ab[0], ab[1], ab[2], ab[3]);
    WI[o]  = make_uint2(bitc<unsigned>(w01), bitc<unsigned>(w23));
}

// ---------------------------------------------------------------------------
// prep: interleaved [c][u][g], P = {An01,An23,B01,B23} (eval16 format)
// ---------------------------------------------------------------------------
__global__ void prep_ilv16(const float* __restrict__ sg, const float* __restrict__ mu,
                           const float* __restrict__ w, const float* __restrict__ er,
                           uint4* __restrict__ P, uint2* __restrict__ WI,
                           int S4, int U, int CPG, int NG)
{
    int i = blockIdx.x * 256 + threadIdx.x;
    if (i >= S4 * U) return;
    int uo = i % U, s4 = i / U;
    int g = s4 / CPG, c = s4 % CPG;
    const float L2E = 1.4426950408889634f;
    float An[4], Bq[4]; __half wh[4];
    #pragma unroll
    for (int q = 0; q < 4; ++q) {
        size_t idx = (size_t)(s4 * 4 + q) * U + uo;
        float a = sg[idx] * L2E;
        An[q] = -a;
        Bq[q] = mu[idx] * a;
        wh[q] = __float2half_rn(w[idx] * er[idx]);
    }
    unsigned an01 = bitc<unsigned>(__floats2half2_rn(An[0], An[1]));
    unsigned an23 = bitc<unsigned>(__floats2half2_rn(An[2], An[3]));
    unsigned b01  = bitc<unsigned>(__floats2half2_rn(Bq[0], Bq[1]));
    unsigned b23  = bitc<unsigned>(__floats2half2_rn(Bq[2], Bq[3]));
    __half2 w01 = __halves2half2(wh[0], wh[1]);
    __half2 w23 = __halves2half2(wh[2], wh[3]);
    int o = (c * U + uo) * NG + g;
    P[o]  = make_uint4(an01, an23, b01, b23);
    WI[o] = make_uint2(bitc<unsigned>(w01), bitc<unsigned>(w23));
}

// linear fp16 pack (producer sens2 pass)
__global__ void prep_half(const float* __restrict__ sg, const float* __restrict__ mu,
                          const float* __restrict__ w, const float* __restrict__ er,
                          __half2* __restrict__ AB, __half* __restrict__ W, int n)
{
    int i = blockIdx.x * 256 + threadIdx.x;
    if (i >= n) return;
    const float L2E = 1.4426950408889634f;
    float a = sg[i] * L2E;
    AB[i] = __floats2half2_rn(a, mu[i] * a);
    W[i]  = __float2half_rn(w[i] * er[i]);
}

__global__ void prep_vec(const float* __restrict__ gleak, const float* __restrict__ vleak,
                         const float* __restrict__ cm,
                         float* __restrict__ cmt, float* __restrict__ nb,
                         float* __restrict__ db, int n)
{
    int i = blockIdx.x * 256 + threadIdx.x;
    if (i >= n) return;
    float c6 = cm[i] * 6.f;
    float gl = gleak[i];
    cmt[i] = c6;
    nb[i]  = gl * vleak[i];
    db[i]  = c6 + gl + 1e-8f;
}

// ---------------------------------------------------------------------------
// Fused pipeline: 128 blocks (r15 structure).
//   blocks 0..63  (producer): ltc1 + per-segment sens2 sums, one release/seg.
//   blocks 64..127 (consumer): ltc2; relaxed-spin + one acquire/seg.
// NEW (r16): consumer's 10 streamed chunks pinned into registers via
// asm "+v" (defeats rematerialization, r11's failure) — zero global reads
// in the unfold loop.
// ---------------------------------------------------------------------------
__global__ __launch_bounds__(1024, 1) void ltc_pipe(
    const float* __restrict__ x,
    const float* __restrict__ iw1, const float* __restrict__ ib1,
    const uint4* __restrict__ ABsI1, const uint2* __restrict__ WsI1,
    const uint4* __restrict__ ABrI1, const uint2* __restrict__ WrI1,
    const float* __restrict__ cmt1, const float* __restrict__ nb1v, const float* __restrict__ db1v,
    const float* __restrict__ ow1, const float* __restrict__ ob1,
    const float* __restrict__ iw2, const float* __restrict__ ib2,
    const __half2* __restrict__ AB2s, const __half* __restrict__ W2sl,
    const uint4* __restrict__ ABrI2, const uint2* __restrict__ WrI2,
    const float* __restrict__ cmt2, const float* __restrict__ nb2v, const float* __restrict__ db2v,
    const float* __restrict__ ow2, const float* __restrict__ ob2,
    float* __restrict__ h1, float* __restrict__ h2,
    float* __restrict__ sn2, float* __restrict__ sd2,
    unsigned* flags)
{
    __shared__ __align__(16) char smem[148736];
    const int tid = threadIdx.x;

    if (blockIdx.x < 64) {
        // ------------------------------ producer ------------------------------
        const int b    = blockIdx.x;
        const int w    = tid >> 6;
        const int lane = tid & 63;
        const int g    = lane & 7;              // 8 groups x 16 rows
        const int ul   = lane >> 3;
        const int u    = w * 8 + ul;            // 128 columns

        uint4* ABl = (uint4*)smem;                                   // 64 KB
        uint2* Wl  = (uint2*)(smem + 65536);                         // 32 KB
        float (*vbuf)[8][20] = (float (*)[8][20])(smem + 98304);     // 1.25 KB
        float* ibuf = (float*)(smem + 99584);                        // 512 B
        float (*ibu)[S2] = (float (*)[S2])(smem + 100096);           // 16 KB

        for (int idx = tid; idx < 4 * 1024; idx += 1024) {
            ABl[idx] = ABrI1[idx];
            Wl[idx]  = WrI1[idx];
        }
        for (int idx = tid; idx < 2 * 8 * 20; idx += 1024)
            (&vbuf[0][0][0])[idx] = 0.f;

        float v_reg = 0.f;
        const float c_cmt = cmt1[u], c_nb = nb1v[u], c_db = db1v[u];
        const float c_ow = ow1[u], c_ob = ob1[u];
        float c_iw = 0.f, c_ib = 0.f;
        if (tid < S1) { c_iw = iw1[tid]; c_ib = ib1[tid]; }

        const float* xb = x  + (size_t)b * T_STEPS * S1;
        float*       hb = h1 + (size_t)b * T_STEPS * U1;
        const uint4* pABs = ABsI1 + tid;
        const uint2* pWs  = WsI1  + tid;

        __syncthreads();
        int buf = 0;

        for (int seg = 0; seg < NSEG; ++seg) {
            for (int ts = 0; ts < SEG_T; ++ts) {
                const int t = seg * SEG_T + ts;
                if (tid < S1) ibuf[tid] = fmaf(xb[(size_t)t * S1 + tid], c_iw, c_ib);
                __syncthreads();
                float an = 0.f, ad = 0.f;
                #pragma unroll
                for (int c = 0; c < 4; ++c) {
                    uint4 ab = pABs[c * 1024];
                    uint2 w2 = pWs[c * 1024];
                    float4 vv = *reinterpret_cast<const float4*>(&ibuf[g * 16 + c * 4]);
                    eval4d(ab, w2, vv, an, ad);
                }
                an += __shfl_xor(an, 1, 64); ad += __shfl_xor(ad, 1, 64);
                an += __shfl_xor(an, 2, 64); ad += __shfl_xor(ad, 2, 64);
                an += __shfl_xor(an, 4, 64); ad += __shfl_xor(ad, 4, 64);
                const float nb_t = c_nb + an, db_t = c_db + ad;

                #pragma unroll 1
                for (int k = 0; k < NUNF; ++k) {
                    float anu = 0.f, adu = 0.f;
                    const float* vb = &vbuf[buf][g][0];
                    #pragma unroll
                    for (int c = 0; c < 4; ++c) {
                        uint4 ab = ABl[c * 1024 + tid];
                        uint2 w2 = Wl[c * 1024 + tid];
                        float4 vv = *reinterpret_cast<const float4*>(&vb[c * 4]);
                        eval4d(ab, w2, vv, anu, adu);
                    }
                    anu += __shfl_xor(anu, 1, 64); adu += __shfl_xor(adu, 1, 64);
                    anu += __shfl_xor(anu, 2, 64); adu += __shfl_xor(adu, 2, 64);
                    anu += __shfl_xor(anu, 4, 64); adu += __shfl_xor(adu, 4, 64);
                    float wn = nb_t + anu;
                    float wd = db_t + adu;
                    v_reg = fmaf(c_cmt, v_reg, wn) * fast_rcp(wd);
                    if (g == 0) vbuf[buf ^ 1][w >> 1][(w & 1) * 8 + ul] = v_reg;
                    buf ^= 1;
                    __syncthreads();
                }
                if (g == 0) hb[(size_t)t * U1 + u] = fmaf(v_reg, c_ow, c_ob);
            }

            // ---- sens2 sums for this segment (producer slack) ----
            __syncthreads();    // drains h1 stores
            for (int idx = tid; idx < SEG_T * S2; idx += 1024) {
                int tt = idx >> 7, s = idx & (S2 - 1);
                ibu[tt][s] = fmaf(hb[(size_t)(seg * SEG_T + tt) * S2 + s], iw2[s], ib2[s]);
            }
            __syncthreads();
            {
                const int u2 = tid & 255, tg = tid >> 8;
                #pragma unroll
                for (int half = 0; half < 2; ++half) {
                    const int tb = tg * 8 + half * 4;
                    float an0 = 0, an1 = 0, an2 = 0, an3 = 0;
                    float ad0 = 0, ad1 = 0, ad2 = 0, ad3 = 0;
                    for (int s = 0; s < S2; ++s) {
                        __half2 ab = AB2s[(size_t)s * U2 + u2];
                        float a  = __low2float(ab);
                        float bb = __high2float(ab);
                        float ww = __half2float(W2sl[(size_t)s * U2 + u2]);
                        float aw = fabsf(ww);
                        float r0 = fast_rcp(1.f + fast_exp2(fmaf(-a, ibu[tb + 0][s], bb)));
                        float r1 = fast_rcp(1.f + fast_exp2(fmaf(-a, ibu[tb + 1][s], bb)));
                        float r2 = fast_rcp(1.f + fast_exp2(fmaf(-a, ibu[tb + 2][s], bb)));
                        float r3 = fast_rcp(1.f + fast_exp2(fmaf(-a, ibu[tb + 3][s], bb)));
                        an0 = fmaf(ww, r0, an0); ad0 = fmaf(aw, r0, ad0);
                        an1 = fmaf(ww, r1, an1); ad1 = fmaf(aw, r1, ad1);
                        an2 = fmaf(ww, r2, an2); ad2 = fmaf(aw, r2, ad2);
                        an3 = fmaf(ww, r3, an3); ad3 = fmaf(aw, r3, ad3);
                    }
                    size_t bo = ((size_t)b * T_STEPS + seg * SEG_T + tb) * U2 + u2;
                    sn2[bo]          = an0; sd2[bo]          = ad0;
                    sn2[bo + U2]     = an1; sd2[bo + U2]     = ad1;
                    sn2[bo + 2 * U2] = an2; sd2[bo + 2 * U2] = ad2;
                    sn2[bo + 3 * U2] = an3; sd2[bo + 3 * U2] = ad3;
                }
            }
            __syncthreads();    // drains sn/sd stores
            if (tid == 0)
                __hip_atomic_store(&flags[b * NSEG + seg], 1u,
                                   __ATOMIC_RELEASE, __HIP_MEMORY_SCOPE_AGENT);
        }
    } else {
        // ------------------------------ consumer ------------------------------
        const int b    = blockIdx.x - 64;
        const int w    = tid >> 6;
        const int lane = tid & 63;
        const int g    = lane & 3;
        const int ul   = lane >> 2;
        const int u    = w * 16 + ul;

        uint4* ABl = (uint4*)smem;                                       // 96 KB
        uint2* Wl  = (uint2*)(smem + 98304);                             // 48 KB
        unsigned (*vbuf)[4][40] = (unsigned (*)[4][40])(smem + 147456);  // 1.25 KB

        for (int idx = tid; idx < RC2 * U2 * 4; idx += 1024) {
            ABl[idx] = ABrI2[idx];
            Wl[idx]  = WrI2[idx];
        }
        for (int idx = tid; idx < 2 * 4 * 40; idx += 1024)
            (&vbuf[0][0][0])[idx] = 0u;

        const uint4* pABr = ABrI2 + u * 4 + g;
        const uint2* pWr  = WrI2  + u * 4 + g;

        // load the 10 streamed chunks ONCE and pin into registers:
        // asm "+v" marks them modified -> rematerializing the load is illegal.
        uint4 rAB[NSTR];
        uint2 rW[NSTR];
        #pragma unroll
        for (int c = 0; c < NSTR; ++c) {
            rAB[c] = pABr[(size_t)(RC2 + c) * 1024];
            rW[c]  = pWr[(size_t)(RC2 + c) * 1024];
        }
        #pragma unroll
        for (int c = 0; c < NSTR; ++c) {
            asm volatile("" : "+v"(rAB[c].x), "+v"(rAB[c].y),
                              "+v"(rAB[c].z), "+v"(rAB[c].w));
            asm volatile("" : "+v"(rW[c].x), "+v"(rW[c].y));
        }

        float v_reg = 0.f;
        const float c_cmt = cmt2[u], c_nb = nb2v[u], c_db = db2v[u];
        float c_ow = 0.f, c_ob = 0.f;
        if (u < 64) { c_ow = ow2[u]; c_ob = ob2[u]; }

        float* op = h2 + (size_t)b * T_STEPS * 64;

        __syncthreads();
        int buf = 0;

        for (int seg = 0; seg < NSEG; ++seg) {
            if (tid == 0) {
                while (__hip_atomic_load(&flags[b * NSEG + seg],
                                         __ATOMIC_RELAXED, __HIP_MEMORY_SCOPE_AGENT) == 0u)
                    __builtin_amdgcn_s_sleep(8);
                (void)__hip_atomic_load(&flags[b * NSEG + seg],
                                        __ATOMIC_ACQUIRE, __HIP_MEMORY_SCOPE_AGENT);
            }
            __syncthreads();

            float pf_n, pf_d;
            {
                size_t ro = ((size_t)b * T_STEPS + seg * SEG_T) * U2 + u;
                pf_n = sn2[ro]; pf_d = sd2[ro];
            }

            for (int ts = 0; ts < SEG_T; ++ts) {
                const int t = seg * SEG_T + ts;
                const float nb_t = c_nb + pf_n;
                const float db_t = c_db + pf_d;
                if (ts + 1 < SEG_T) {
                    size_t ro = ((size_t)b * T_STEPS + t + 1) * U2 + u;
                    pf_n = sn2[ro]; pf_d = sd2[ro];
                }

                #pragma unroll 1
                for (int k = 0; k < NUNF; ++k) {
                    float an = 0.f, ad = 0.f;
                    const unsigned* vb = &vbuf[buf][g][0];
                    // LDS-resident chunk pairs
                    #pragma unroll
                    for (int cc = 0; cc < RC2 / 2; ++cc) {
                        uint4 vv = *reinterpret_cast<const uint4*>(&vb[4 * cc]);
                        eval16(ABl[(2 * cc) * 1024 + tid],     Wl[(2 * cc) * 1024 + tid],     vv.x, vv.y, an, ad);
                        eval16(ABl[(2 * cc + 1) * 1024 + tid], Wl[(2 * cc + 1) * 1024 + tid], vv.z, vv.w, an, ad);
                    }
                    // register-resident chunk pairs (static indices, full unroll)
                    #pragma unroll
                    for (int cc = RC2 / 2; cc < 8; ++cc) {
                        uint4 vv = *reinterpret_cast<const uint4*>(&vb[4 * cc]);
                        const int c0 = 2 * cc - RC2;
                        eval16(rAB[c0],     rW[c0],     vv.x, vv.y, an, ad);
                        eval16(rAB[c0 + 1], rW[c0 + 1], vv.z, vv.w, an, ad);
                    }
                    an += __shfl_xor(an, 1, 64); ad += __shfl_xor(ad, 1, 64);
                    an += __shfl_xor(an, 2, 64); ad += __shfl_xor(ad, 2, 64);
                    float wn = nb_t + an;
                    float wd = db_t + ad;
                    v_reg = fmaf(c_cmt, v_reg, wn) * fast_rcp(wd);
                    float v_nx = __shfl_down(v_reg, 4, 64);
                    if (g == 0 && !(ul & 1))
                        vbuf[buf ^ 1][w >> 2][(w & 3) * 8 + (ul >> 1)] =
                            bitc<unsigned>(pkrtz(v_reg, v_nx));
                    buf ^= 1;
                    __syncthreads();
                }
                if (u < 64 && g == 0) op[(size_t)t * 64 + u] = fmaf(v_reg, c_ow, c_ob);
            }
        }
    }
}

// ---------------------------------------------------------------------------
// FC head: out[b,t,o] = fcb[o] + sum_k h2[b,t,k] * fcw[o,k]
// ---------------------------------------------------------------------------
__global__ __launch_bounds__(512, 1) void fc_head(
    const float* __restrict__ h2, const float* __restrict__ fcw,
    const float* __restrict__ fcb, float* __restrict__ out)
{
    __shared__ float fwT[64 * 64];
    __shared__ float hs[8 * 64];
    const int tid = threadIdx.x;
    for (int i = tid; i < 64 * 64; i += 512) {
        int o = i >> 6, k = i & 63;
        fwT[k * 64 + o] = fcw[i];
    }
    size_t base = (size_t)blockIdx.x * 8 * 64;
    hs[tid] = h2[base + tid];
    __syncthreads();
    const int o = tid & 63, tt = tid >> 6;
    float acc = fcb[o];
    #pragma unroll
    for (int k = 0; k < 64; ++k)
        acc = fmaf(hs[tt * 64 + k], fwT[k * 64 + o], acc);
    out[base + tt * 64 + o] = acc;
}

// ---------------------------------------------------------------------------
extern "C" void kernel_launch(void* const* d_in, const int* in_sizes, int n_in,
                              void* d_out, int out_size, void* d_ws, size_t ws_size,
                              hipStream_t stream)
{
    (void)in_sizes; (void)n_in; (void)out_size; (void)ws_size;

    const float* x      = (const float*)d_in[0];
    const float* l1_iw  = (const float*)d_in[1];
    const float* l1_ib  = (const float*)d_in[2];
    const float* l1_sw  = (const float*)d_in[3];
    const float* l1_ss  = (const float*)d_in[4];
    const float* l1_smu = (const float*)d_in[5];
    const float* l1_se  = (const float*)d_in[6];
    const float* l1_w   = (const float*)d_in[8];
    const float* l1_sg  = (const float*)d_in[9];
    const float* l1_mu  = (const float*)d_in[10];
    const float* l1_er  = (const float*)d_in[11];
    const float* l1_gl  = (const float*)d_in[13];
    const float* l1_vl  = (const float*)d_in[14];
    const float* l1_cm  = (const float*)d_in[15];
    const float* l1_ow  = (const float*)d_in[16];
    const float* l1_ob  = (const float*)d_in[17];
    const float* l2_iw  = (const float*)d_in[18];
    const float* l2_ib  = (const float*)d_in[19];
    const float* l2_sw  = (const float*)d_in[20];
    const float* l2_ss  = (const float*)d_in[21];
    const float* l2_smu = (const float*)d_in[22];
    const float* l2_se  = (const float*)d_in[23];
    const float* l2_w   = (const float*)d_in[25];
    const float* l2_sg  = (const float*)d_in[26];
    const float* l2_mu  = (const float*)d_in[27];
    const float* l2_er  = (const float*)d_in[28];
    const float* l2_gl  = (const float*)d_in[30];
    const float* l2_vl  = (const float*)d_in[31];
    const float* l2_cm  = (const float*)d_in[32];
    const float* l2_ow  = (const float*)d_in[33];
    const float* l2_ob  = (const float*)d_in[34];
    const float* fcw    = (const float*)d_in[35];
    const float* fcb    = (const float*)d_in[36];

    char*  base = (char*)d_ws;
    size_t off  = 0;
    auto alloc = [&](size_t bytes) -> char* {
        char* p = base + off;
        off += (bytes + 255) & ~(size_t)255;
        return p;
    };

    float* h1 = (float*)alloc((size_t)B_SZ * T_STEPS * U1 * 4);
    float* h2 = (float*)alloc((size_t)B_SZ * T_STEPS * 64 * 4);
    uint4* ABsI1 = (uint4*)alloc((size_t)(S1 / 4) * U1 * 16);
    uint2* WsI1  = (uint2*)alloc((size_t)(S1 / 4) * U1 * 8);
    uint4* ABrI1 = (uint4*)alloc((size_t)(U1 / 4) * U1 * 16);
    uint2* WrI1  = (uint2*)alloc((size_t)(U1 / 4) * U1 * 8);
    uint4* ABrI2 = (uint4*)alloc((size_t)(U2 / 4) * U2 * 16);
    uint2* WrI2  = (uint2*)alloc((size_t)(U2 / 4) * U2 * 8);
    __half2* AB2s = (__half2*)alloc((size_t)S2 * U2 * 4);
    __half*  W2s  = (__half*) alloc((size_t)S2 * U2 * 2);
    float* cmt1 = (float*)alloc(U1 * 4);
    float* nb1  = (float*)alloc(U1 * 4);
    float* db1  = (float*)alloc(U1 * 4);
    float* cmt2 = (float*)alloc(U2 * 4);
    float* nb2  = (float*)alloc(U2 * 4);
    float* db2  = (float*)alloc(U2 * 4);
    float* sn2  = (float*)alloc((size_t)B_SZ * T_STEPS * U2 * 4);
    float* sd2  = (float*)alloc((size_t)B_SZ * T_STEPS * U2 * 4);
    unsigned* flags = (unsigned*)alloc((size_t)B_SZ * NSEG * 4);

    hipMemsetAsync(flags, 0, (size_t)B_SZ * NSEG * 4, stream);

    prep_ilv<<<((S1/4)*U1 + 255)/256, 256, 0, stream>>>(l1_ss, l1_smu, l1_sw, l1_se, ABsI1, WsI1, S1/4, U1, 4, 8);
    prep_ilv<<<((U1/4)*U1 + 255)/256, 256, 0, stream>>>(l1_sg, l1_mu,  l1_w,  l1_er, ABrI1, WrI1, U1/4, U1, 4, 8);
    prep_ilv16<<<((U2/4)*U2 + 255)/256, 256, 0, stream>>>(l2_sg, l2_mu, l2_w, l2_er, ABrI2, WrI2, U2/4, U2, 16, 4);
    prep_half<<<(S2 * U2 + 255)/256, 256, 0, stream>>>(l2_ss, l2_smu, l2_sw, l2_se, AB2s, W2s, S2 * U2);
    prep_vec<<<1, 256, 0, stream>>>(l1_gl, l1_vl, l1_cm, cmt1, nb1, db1, U1);
    prep_vec<<<1, 256, 0, stream>>>(l2_gl, l2_vl, l2_cm, cmt2, nb2, db2, U2);

    ltc_pipe<<<128, 1024, 0, stream>>>(
        x, l1_iw, l1_ib, ABsI1, WsI1, ABrI1, WrI1, cmt1, nb1, db1, l1_ow, l1_ob,
        l2_iw, l2_ib, AB2s, W2s, ABrI2, WrI2, cmt2, nb2, db2, l2_ow, l2_ob,
        h1, h2, sn2, sd2, flags);

    fc_head<<<B_SZ * T_STEPS / 8, 512, 0, stream>>>(h2, fcw, fcb, (float*)d_out);
}